// Round 1
// baseline (349.586 us; speedup 1.0000x reference)
//
#include <hip/hip_runtime.h>
#include <hip/hip_fp16.h>
#include <hip/hip_cooperative_groups.h>

namespace cg = cooperative_groups;

// ---------------------------------------------------------------------------
// Abbe lithography forward — single cooperative kernel (fused R6 structure).
// Math identical to the 5-kernel version: doses factor out (I(d)=d^2 I(1));
// shift phases cancel in |AA|^2; weight cancels against norm_I; +/- source
// pairs merged (exact: Hermitian W about window center + odd-symmetric FM).
// Phases (grid.sync between):
//   B1: block0 setup (weights+pair-merge+scale -> ws hdr); rows FFT of mask,
//       keep 241 window cols                                -> R1t[beta][y]
//   B2: col FFT, keep 241 window rows                       -> W[alpha][beta]
//   C1: per (source,alpha-pair) row IDFT of (W.*P)*sqrt(w)/512 -> T2 fp16,
//       layout [sic][col/4][x][4] (coalesced float4 stores).
//       rows with fl(G^2)>1 provably all-zero -> skip FFT, store zeros.
//   C2: per source col IDFT, acc[part][x][y] = sum |AA'|^2
//   D : transpose 32x32 tiles, scale, 3 doses, resist sigmoid
// FFT-512: radix-8, 3 stages, one wave per FFT, wave-level sync only.
// Twiddle (f64-built) + FM tables built ONCE per block (was: per kernel).
// launch_bounds(256,4): VGPR cap 128 (no spills in wfft512), 4 blocks/CU
// co-resident -> cooperative grid of <=1024 blocks is safe (checked at
// launch via hipOccupancyMaxActiveBlocksPerMultiprocessor).
// ---------------------------------------------------------------------------

#define SPLIT 8

static const size_t O_ACC  = 8192;                       // SPLIT*512*512*f32
static const size_t ACC_BYTES = (size_t)SPLIT * 512 * 512 * 4;
static const size_t O_WIN  = O_ACC + ACC_BYTES;
static const size_t O_R1   = O_WIN + 464896;
static const size_t O_T2   = O_R1 + 987136;
static const size_t SLOT_BYTES = (size_t)512 * 244 * 4;  // half2 slots (=61*512*4*4B)

__device__ inline float2 cadd(float2 a, float2 b){ return make_float2(a.x+b.x, a.y+b.y); }
__device__ inline float2 csub(float2 a, float2 b){ return make_float2(a.x-b.x, a.y-b.y); }
__device__ inline float2 cmul(float2 a, float2 b){
  return make_float2(fmaf(a.x, b.x, -(a.y*b.y)), fmaf(a.x, b.y, a.y*b.x));
}
__device__ inline float2 twsgn(float2 t, int S) {
  return make_float2(t.x, (S > 0) ? t.y : -t.y);
}

// Per-block twiddle table exp(+2*pi*i*k/512), f64-built (256-thread blocks).
__device__ inline void build_twt(float2* twt) {
  for (int k = (int)threadIdx.x; k < 512; k += 256) {
    double a = 6.283185307179586476925286766559 * (double)k / 512.0;
    twt[k] = make_float2((float)cos(a), (float)sin(a));
  }
}

// Radix-8 butterfly. If ZTOP, v[4..7] are known zero (skips first add level).
template<int S, bool ZTOP>
__device__ inline void dft8(float2 v[8]) {
  const float sg = (float)S;
  const float C7 = 0.7071067811865476f;
  float2 t0, t1, t2, t3, t4, t5, t6, t7;
  if (ZTOP) {
    t0 = v[0]; t4 = v[0];
    t1 = v[1]; t5 = v[1];
    t2 = v[2]; t6 = v[2];
    t3 = v[3]; t7 = v[3];
  } else {
    t0=cadd(v[0],v[4]); t4=csub(v[0],v[4]);
    t1=cadd(v[1],v[5]); t5=csub(v[1],v[5]);
    t2=cadd(v[2],v[6]); t6=csub(v[2],v[6]);
    t3=cadd(v[3],v[7]); t7=csub(v[3],v[7]);
  }
  t5 = make_float2(C7*(t5.x - sg*t5.y), C7*(t5.y + sg*t5.x));
  t6 = make_float2(-sg*t6.y, sg*t6.x);
  t7 = make_float2(C7*(-t7.x - sg*t7.y), C7*(sg*t7.x - t7.y));
  float2 u0=cadd(t0,t2), u2=csub(t0,t2);
  float2 u1=cadd(t1,t3), u3=csub(t1,t3);
  u3 = make_float2(-sg*u3.y, sg*u3.x);
  float2 u4=cadd(t4,t6), u6=csub(t4,t6);
  float2 u5=cadd(t5,t7), u7=csub(t5,t7);
  u7 = make_float2(-sg*u7.y, sg*u7.x);
  v[0]=cadd(u0,u1); v[4]=csub(u0,u1);
  v[2]=cadd(u2,u3); v[6]=csub(u2,u3);
  v[1]=cadd(u4,u5); v[5]=csub(u4,u5);
  v[3]=cadd(u6,u7); v[7]=csub(u6,u7);
}

// One-wave FFT-512; xch = per-wave float2[544] (16B aligned). Wave-sync only.
template<int S, bool ZTOP>
__device__ inline void wfft512(float2 v[8], int lane, float2* xch,
                               const float2* twt) {
  const int p2 = lane & 7, u0 = lane >> 3;
  dft8<S, ZTOP>(v);
  { float2 t1 = twsgn(twt[lane], S), acc = t1;
    v[1] = cmul(v[1], acc);
    #pragma unroll
    for (int u = 2; u < 8; u++) { acc = cmul(acc, t1); v[u] = cmul(v[u], acc); } }
  __builtin_amdgcn_wave_barrier();
  #pragma unroll
  for (int u = 0; u < 8; u++) xch[u*68 + p2*8 + u0] = v[u];
  __builtin_amdgcn_wave_barrier();
  { const float4* rp = (const float4*)(xch + u0*68 + p2*8);
    #pragma unroll
    for (int q = 0; q < 4; q++) {
      float4 t = rp[q];
      v[2*q]   = make_float2(t.x, t.y);
      v[2*q+1] = make_float2(t.z, t.w);
    } }
  dft8<S, false>(v);
  { float2 t1 = twsgn(twt[p2 << 3], S), acc = t1;
    v[1] = cmul(v[1], acc);
    #pragma unroll
    for (int u = 2; u < 8; u++) { acc = cmul(acc, t1); v[u] = cmul(v[u], acc); } }
  __builtin_amdgcn_wave_barrier();
  #pragma unroll
  for (int u = 0; u < 8; u++) xch[u*68 + lane] = v[u];
  __builtin_amdgcn_wave_barrier();
  { const float4* rp = (const float4*)(xch + p2*68 + u0*8);
    #pragma unroll
    for (int q = 0; q < 4; q++) {
      float4 t = rp[q];
      v[2*q]   = make_float2(t.x, t.y);
      v[2*q+1] = make_float2(t.z, t.w);
    } }
  dft8<S, false>(v);
}

__global__ void __launch_bounds__(256, 4)
k_fused(const float* __restrict__ mask, const float* __restrict__ prm,
        const float* __restrict__ sfx, const float* __restrict__ sfy,
        char* ws, float2* R1t, float2* Wg, __half2* T2, float* acc,
        float* out, int CH) {
  cg::grid_group grid = cg::this_grid();
  const int t = threadIdx.x, lane = t & 63, wv = t >> 6;
  __shared__ __align__(16) float2 lds[4*544];
  __shared__ __align__(16) float2 twt[512];
  __shared__ float FMt[241];
  build_twt(twt);
  if (t < 241) FMt[t] = (float)(((double)(t - 120)) / 100.0);
  float2* const xch = lds + wv*544;

  // ---------------- phase B1: setup (block 0) + row FFTs -------------------
  if (blockIdx.x == 0) {
    float*  sw  = (float*)lds;                 // scratch overlay (pre-FFT)
    float*  sxx = sw + 192; float* syy = sxx + 192; float* scw = syy + 192;
    double* so  = (double*)(sw + 768);
    int*    skp = (int*)(so + 176);
    if (t < 169) {
      float p = prm[t];
      float val = 1.f / (1.f + __expf(-8.f * p));
      float w = (val >= 0.001f) ? val : 0.f;
      double o = 0.0; float fx = 0.f, fy = 0.f;
      if (w > 0.f) {
        fx = sfx[t]; fy = sfy[t];
        double f2 = (double)fx*(double)fx + (double)fy*(double)fy;
        o = (double)w * sqrt((1.0 - 0.11390625 * f2) / (1.0 - 0.87890625 * f2));
      }
      sw[t] = w; so[t] = o; sxx[t] = fx; syy[t] = fy;
    }
    __syncthreads();
    if (t < 169) {                      // merge s with s'=(-fx,-fy): exact
      float w = sw[t];
      int keep = 0; float cw = w;
      if (w > 0.f) {
        float fx = sxx[t], fy = syy[t];
        int pr = -1;
        for (int s2 = 0; s2 < 169; s2++) {
          if (sw[s2] > 0.f && fabsf(sxx[s2] + fx) < 1e-5f
                           && fabsf(syy[s2] + fy) < 1e-5f) { pr = s2; break; }
        }
        if (pr < 0 || pr == t) keep = 1;
        else if (pr > t) { keep = 1; cw = w + sw[pr]; }
      }
      skp[t] = keep; scw[t] = cw;
    }
    __syncthreads();
    if (t == 0) {
      float* wsfw = (float*)ws;
      double Sden = 0.0; int c = 0;
      for (int s = 0; s < 169; s++) {
        Sden += so[s];                               // norm over ALL valid
        if (skp[s]) { wsfw[64+c] = scw[s]; wsfw[320+c] = sxx[s]; wsfw[576+c] = syy[s]; c++; }
      }
      ((int*)ws)[0] = c;
      wsfw[1] = (float)(1.0 / (262144.0 * 1.44 * Sden));  // 512^2 refold
    }
  }
  __syncthreads();                              // setup scratch dead; twt ready
  for (int rb = blockIdx.x; rb < 128; rb += gridDim.x) {
    int y = rb * 4 + wv;
    float2 v[8];
    #pragma unroll
    for (int q = 0; q < 8; q++) v[q] = make_float2(mask[y*512 + 64*q + lane], 0.f);
    wfft512<-1, false>(v, lane, xch, twt);
    #pragma unroll
    for (int u = 0; u < 8; u++) {
      int k = (lane>>3) + 8*(lane&7) + 64*u;
      int beta = (k >= 392) ? (k - 392) : ((k <= 120) ? (k + 120) : -1);
      if (beta >= 0) R1t[beta*512 + y] = v[u];
    }
  }
  grid.sync();

  // ---------------- phase B2: col FFT -> W[alpha][beta] --------------------
  for (int jb = blockIdx.x; jb < 61; jb += gridDim.x) {
    int j = jb * 4 + wv;                        // beta 0..243
    float2 v[8];
    #pragma unroll
    for (int q = 0; q < 8; q++)
      v[q] = (j < 241) ? R1t[j*512 + 64*q + lane] : make_float2(0.f, 0.f);
    wfft512<-1, false>(v, lane, xch, twt);
    if (j < 241) {
      #pragma unroll
      for (int u = 0; u < 8; u++) {
        int k = (lane>>3) + 8*(lane&7) + 64*u;
        int alpha = (k >= 392) ? (k - 392) : ((k <= 120) ? (k + 120) : -1);
        if (alpha >= 0) Wg[alpha*241 + j] = v[u];
      }
    }
  }
  grid.sync();

  const float* wsf = (const float*)ws;
  const int count = *(const int*)ws;
  int nb = (count + CH - 1) / CH;
  if (nb < 1) nb = 1;                           // count==0 still zero-fills acc
  for (int bi = 0; bi < nb; bi++) {
    const int base = bi * CH;
    int active = count - base;
    if (active > CH) active = CH;
    if (active < 0) active = 0;
    const int ntask = active * 31;

    // -------- phase C1: row IDFT of (W.*P)*sqrt(w)/512 -> T2 fp16 ---------
    for (int task = blockIdx.x; task < ntask; task += gridDim.x) {
      int sic  = task / 31;
      int tile = task % 31;                    // 8 alphas/tile, 2 phases of 4
      int slot = base + sic;
      float fx = wsf[320 + slot], fy = wsf[576 + slot];
      float sqw = __fsqrt_rn(wsf[64 + slot]) * 0.001953125f;  // sqrt(w)/512
      #pragma unroll
      for (int ph = 0; ph < 2; ph++) {
        int alpha = tile*8 + ph*4 + wv;
        bool arow = (alpha < 241);
        float Gf = __fadd_rn(arow ? FMt[alpha] : 0.f, fy);
        float g2 = __fmul_rn(Gf, Gf);
        bool active_row = arow && (g2 <= 1.0f); // fl(G^2)>1 -> row all-zero
        float2 v[8];
        #pragma unroll
        for (int q = 0; q < 8; q++) v[q] = make_float2(0.f, 0.f);
        if (active_row) {
          #pragma unroll
          for (int q = 0; q < 4; q++) {        // n<241 -> q<4 only
            int n = 64*q + lane;
            if (n < 241) {
              float Ff = __fadd_rn(FMt[n], fx);
              float r2 = __fadd_rn(__fmul_rn(Ff, Ff), g2);  // np f32 semantics
              if (r2 <= 1.0f) {
                float num = fmaf(-0.11390625f, r2, 1.0f);
                float den = fmaf(-0.87890625f, r2, 1.0f);
                float P = __fsqrt_rn(__fsqrt_rn(__fdividef(num, den))) * sqw;
                float2 Wv = Wg[alpha*241 + n];
                v[q] = make_float2(P * Wv.x, P * Wv.y);
              }
            }
          }
          wfft512<1, true>(v, lane, xch, twt);
        }
        #pragma unroll
        for (int u = 0; u < 8; u++) {
          int xx = (lane>>3) + 8*(lane&7) + 64*u;
          xch[xx] = v[u];                      // zeros when inactive
        }
        __syncthreads();
        int colb = tile*8 + ph*4;
        if (colb < 244) {                      // tile30/ph1 would spill: skip
          #pragma unroll
          for (int r = 0; r < 2; r++) {
            int x = t + 256*r;
            union { __half2 h[4]; float4 f; } uu;
            #pragma unroll
            for (int wvi = 0; wvi < 4; wvi++) {
              float2 a = lds[wvi*544 + x];
              uu.h[wvi] = __floats2half2_rn(a.x, a.y);
            }
            // T2 layout [sic][col/4][x][4]: consecutive x -> contiguous 16B
            *(float4*)(T2 + ((size_t)(sic*61 + (colb>>2))*512 + x)*4) = uu.f;
          }
        }
        __syncthreads();
      }
    }
    grid.sync();

    // -------- phase C2: col IDFT per source, acc += |AA'|^2 ---------------
    for (int unit = blockIdx.x; unit < 1024; unit += gridDim.x) {
      int part = unit & 7;
      int x = (unit >> 3) * 4 + wv;
      float av[8] = {0.f,0.f,0.f,0.f,0.f,0.f,0.f,0.f};
      int sic = part;
      bool act = (sic < CH) && (base + sic < count);
      __half2 pv[4] = {{0.f,0.f},{0.f,0.f},{0.f,0.f},{0.f,0.f}};
      if (act) {
        const __half2* sp = T2 + (size_t)sic * (61*512*4);
        #pragma unroll
        for (int q = 0; q < 4; q++) {
          int n = 64*q + lane;
          pv[q] = (n < 241) ? sp[((size_t)(n>>2)*512 + x)*4 + (n&3)]
                            : __half2{0.f, 0.f};
        }
      }
      while (act) {
        float2 v[8];
        #pragma unroll
        for (int q = 0; q < 4; q++) v[q] = __half22float2(pv[q]);
        #pragma unroll
        for (int q = 4; q < 8; q++) v[q] = make_float2(0.f, 0.f);
        int nsic = sic + SPLIT;
        act = (nsic < CH) && (base + nsic < count);
        if (act) {                             // prefetch across the FFT
          const __half2* sp = T2 + (size_t)nsic * (61*512*4);
          #pragma unroll
          for (int q = 0; q < 4; q++) {
            int n = 64*q + lane;
            pv[q] = (n < 241) ? sp[((size_t)(n>>2)*512 + x)*4 + (n&3)]
                              : __half2{0.f, 0.f};
          }
        }
        wfft512<1, true>(v, lane, xch, twt);
        #pragma unroll
        for (int u = 0; u < 8; u++)
          av[u] += fmaf(v[u].x, v[u].x, v[u].y*v[u].y);
        sic = nsic;
      }
      float* a = acc + ((size_t)part << 18) + (size_t)x * 512;
      int y0 = (lane>>3) + 8*(lane&7);
      if (bi == 0) {
        #pragma unroll
        for (int u = 0; u < 8; u++) a[y0 + 64*u] = av[u];
      } else {
        #pragma unroll
        for (int u = 0; u < 8; u++) a[y0 + 64*u] += av[u];
      }
    }
    grid.sync();
  }

  // ---------------- phase D: transpose, scale, doses, resist ---------------
  {
    float scale = wsf[1];
    float (*tile2)[33] = reinterpret_cast<float(*)[33]>((float*)lds);
    const float dd[3] = {0.9604f, 1.0f, 1.0404f};
    int tx = t & 31, ty0 = t >> 5;
    for (int tb = blockIdx.x; tb < 256; tb += gridDim.x) {
      int x0 = (tb & 15) * 32, y0 = (tb >> 4) * 32;
      #pragma unroll
      for (int r = 0; r < 4; r++) {
        int i = ty0 + 8*r;
        const float* ap = acc + (size_t)(x0 + i)*512 + y0 + tx;
        float s = 0.f;
        #pragma unroll
        for (int p = 0; p < SPLIT; p++) s += ap[(size_t)p << 18];
        tile2[i][tx] = s;
      }
      __syncthreads();
      #pragma unroll
      for (int r = 0; r < 4; r++) {
        int yy = ty0 + 8*r;
        float I = scale * tile2[tx][yy];
        int o = (y0 + yy)*512 + x0 + tx;
        #pragma unroll
        for (int d = 0; d < 3; d++) {
          float Ik = dd[d] * I;
          out[(size_t)d*262144 + o] = Ik;
          out[(size_t)(3+d)*262144 + o] = 1.f / (1.f + __expf(-30.f*(Ik - 0.225f)));
        }
      }
      __syncthreads();
    }
  }
}

extern "C" void kernel_launch(void* const* d_in, const int* in_sizes, int n_in,
                              void* d_out, int out_size, void* d_ws, size_t ws_size,
                              hipStream_t stream) {
  (void)in_sizes; (void)n_in; (void)out_size;
  const float* mask = (const float*)d_in[0];
  const float* prm  = (const float*)d_in[1];
  const float* sfx  = (const float*)d_in[2];
  const float* sfy  = (const float*)d_in[3];
  float* out = (float*)d_out;
  char*  ws  = (char*)d_ws;

  float*   acc = (float*)(ws + O_ACC);
  float2*  Wg  = (float2*)(ws + O_WIN);
  float2*  R1t = (float2*)(ws + O_R1);
  __half2* T2  = (__half2*)(ws + O_T2);

  size_t avail = (ws_size > O_T2) ? (ws_size - O_T2) : 0;
  int CH = (int)(avail / SLOT_BYTES);
  if (CH > 169) CH = 169;
  if (CH < 1)   CH = 1;

  // Cooperative grid size: occupancy-derived (cached), capped at 1024 units.
  static int grid_blocks = 0;
  if (grid_blocks == 0) {
    int nbk = 0;
    if (hipOccupancyMaxActiveBlocksPerMultiprocessor(
            &nbk, (const void*)k_fused, 256, 0) != hipSuccess || nbk < 1)
      nbk = 1;
    int ncu = 256;
    hipDeviceProp_t prop;
    int dev = 0;
    if (hipGetDevice(&dev) == hipSuccess &&
        hipGetDeviceProperties(&prop, dev) == hipSuccess &&
        prop.multiProcessorCount > 0)
      ncu = prop.multiProcessorCount;
    long g = (long)nbk * (long)ncu;
    if (g > 1024) g = 1024;
    if (g < 1) g = 1;
    grid_blocks = (int)g;
  }

  void* args[] = { (void*)&mask, (void*)&prm, (void*)&sfx, (void*)&sfy,
                   (void*)&ws, (void*)&R1t, (void*)&Wg, (void*)&T2,
                   (void*)&acc, (void*)&out, (void*)&CH };
  hipLaunchCooperativeKernel((const void*)k_fused, dim3(grid_blocks), dim3(256),
                             args, 0, stream);
}

// Round 2
// 320.223 us; speedup vs baseline: 1.0917x; 1.0917x over previous
//
#include <hip/hip_runtime.h>
#include <hip/hip_fp16.h>

// ---------------------------------------------------------------------------
// Abbe lithography forward — single cooperative-launched kernel with a
// CUSTOM epoch grid-barrier (cg::grid.sync measured ~50-70us/sync on this
// 8-XCD chip in R1; hand-rolled barrier = 1 relaxed atomicAdd + s_sleep(1)
// spin + one threadfence pair per block, expected ~5-10us).
// Math identical to the verified 5-kernel version: doses factor out
// (I(d)=d^2 I(1)); shift phases cancel in |AA|^2; weight cancels against
// norm_I; +/- source pairs merged (exact).
// Phases (custom gbar between):
//   B1: block0 setup -> ws hdr; rows FFT of mask, keep 241 cols -> R1t
//   B2: col FFT, keep 241 rows -> W[alpha][beta]
//   C1: per (source,tile) row IDFT of (W.*P)*sqrt(w)/512 -> T2 fp16
//       (T2 layout [sic][x][col] — C2-read-coalesced, as in the 139us split)
//   C2: per source col IDFT, acc[part][x][y] = sum |AA'|^2
//   D : transpose 32x32 tiles, scale, 3 doses, resist sigmoid
// FFT-512: radix-8, 3 stages, one wave per FFT, wave-level sync only.
// Barrier counters in ws[+4096]; zeroed by captured hipMemsetAsync.
// ---------------------------------------------------------------------------

#define SPLIT 8

static const size_t O_BAR  = 4096;                       // cnt @+4096, gen @+4160
static const size_t O_ACC  = 8192;                       // SPLIT*512*512*f32
static const size_t ACC_BYTES = (size_t)SPLIT * 512 * 512 * 4;
static const size_t O_WIN  = O_ACC + ACC_BYTES;
static const size_t O_R1   = O_WIN + 464896;
static const size_t O_T2   = O_R1 + 987136;
static const size_t SLOT_BYTES = (size_t)512 * 244 * 4;  // half2 slots

__device__ inline float2 cadd(float2 a, float2 b){ return make_float2(a.x+b.x, a.y+b.y); }
__device__ inline float2 csub(float2 a, float2 b){ return make_float2(a.x-b.x, a.y-b.y); }
__device__ inline float2 cmul(float2 a, float2 b){
  return make_float2(fmaf(a.x, b.x, -(a.y*b.y)), fmaf(a.x, b.y, a.y*b.x));
}
__device__ inline float2 twsgn(float2 t, int S) {
  return make_float2(t.x, (S > 0) ? t.y : -t.y);
}

// Custom epoch grid-barrier. All blocks call with the same sequence count.
// cnt/gen zeroed before launch. One atomicAdd per block; tid0 spins relaxed
// with s_sleep(1); one threadfence (release) before arrive and one
// (acquire) after release observed.
__device__ inline void gbar(unsigned* cnt, unsigned* gen, unsigned nblk,
                            unsigned& ep) {
  __syncthreads();
  ep++;
  if (threadIdx.x == 0) {
    const unsigned target = ep;
    __threadfence();                           // release: drain my writes
    unsigned old = __hip_atomic_fetch_add(cnt, 1u, __ATOMIC_RELAXED,
                                          __HIP_MEMORY_SCOPE_AGENT);
    if (old == nblk - 1u) {                    // last arriver of this epoch
      __hip_atomic_store(cnt, 0u, __ATOMIC_RELAXED, __HIP_MEMORY_SCOPE_AGENT);
      __hip_atomic_store(gen, target, __ATOMIC_RELEASE,
                         __HIP_MEMORY_SCOPE_AGENT);
    } else {
      while (__hip_atomic_load(gen, __ATOMIC_RELAXED,
                               __HIP_MEMORY_SCOPE_AGENT) < target)
        __builtin_amdgcn_s_sleep(1);
    }
    __threadfence();                           // acquire: invalidate caches
  }
  __syncthreads();
}

// Per-block twiddle table exp(+2*pi*i*k/512), f64-built (256-thread blocks).
__device__ inline void build_twt(float2* twt) {
  for (int k = (int)threadIdx.x; k < 512; k += 256) {
    double a = 6.283185307179586476925286766559 * (double)k / 512.0;
    twt[k] = make_float2((float)cos(a), (float)sin(a));
  }
}

// Radix-8 butterfly. If ZTOP, v[4..7] are known zero (skips first add level).
template<int S, bool ZTOP>
__device__ inline void dft8(float2 v[8]) {
  const float sg = (float)S;
  const float C7 = 0.7071067811865476f;
  float2 t0, t1, t2, t3, t4, t5, t6, t7;
  if (ZTOP) {
    t0 = v[0]; t4 = v[0];
    t1 = v[1]; t5 = v[1];
    t2 = v[2]; t6 = v[2];
    t3 = v[3]; t7 = v[3];
  } else {
    t0=cadd(v[0],v[4]); t4=csub(v[0],v[4]);
    t1=cadd(v[1],v[5]); t5=csub(v[1],v[5]);
    t2=cadd(v[2],v[6]); t6=csub(v[2],v[6]);
    t3=cadd(v[3],v[7]); t7=csub(v[3],v[7]);
  }
  t5 = make_float2(C7*(t5.x - sg*t5.y), C7*(t5.y + sg*t5.x));
  t6 = make_float2(-sg*t6.y, sg*t6.x);
  t7 = make_float2(C7*(-t7.x - sg*t7.y), C7*(sg*t7.x - t7.y));
  float2 u0=cadd(t0,t2), u2=csub(t0,t2);
  float2 u1=cadd(t1,t3), u3=csub(t1,t3);
  u3 = make_float2(-sg*u3.y, sg*u3.x);
  float2 u4=cadd(t4,t6), u6=csub(t4,t6);
  float2 u5=cadd(t5,t7), u7=csub(t5,t7);
  u7 = make_float2(-sg*u7.y, sg*u7.x);
  v[0]=cadd(u0,u1); v[4]=csub(u0,u1);
  v[2]=cadd(u2,u3); v[6]=csub(u2,u3);
  v[1]=cadd(u4,u5); v[5]=csub(u4,u5);
  v[3]=cadd(u6,u7); v[7]=csub(u6,u7);
}

// One-wave FFT-512; xch = per-wave float2[544] (16B aligned). Wave-sync only.
template<int S, bool ZTOP>
__device__ inline void wfft512(float2 v[8], int lane, float2* xch,
                               const float2* twt) {
  const int p2 = lane & 7, u0 = lane >> 3;
  dft8<S, ZTOP>(v);
  { float2 t1 = twsgn(twt[lane], S), acc = t1;
    v[1] = cmul(v[1], acc);
    #pragma unroll
    for (int u = 2; u < 8; u++) { acc = cmul(acc, t1); v[u] = cmul(v[u], acc); } }
  __builtin_amdgcn_wave_barrier();
  #pragma unroll
  for (int u = 0; u < 8; u++) xch[u*68 + p2*8 + u0] = v[u];
  __builtin_amdgcn_wave_barrier();
  { const float4* rp = (const float4*)(xch + u0*68 + p2*8);
    #pragma unroll
    for (int q = 0; q < 4; q++) {
      float4 t = rp[q];
      v[2*q]   = make_float2(t.x, t.y);
      v[2*q+1] = make_float2(t.z, t.w);
    } }
  dft8<S, false>(v);
  { float2 t1 = twsgn(twt[p2 << 3], S), acc = t1;
    v[1] = cmul(v[1], acc);
    #pragma unroll
    for (int u = 2; u < 8; u++) { acc = cmul(acc, t1); v[u] = cmul(v[u], acc); } }
  __builtin_amdgcn_wave_barrier();
  #pragma unroll
  for (int u = 0; u < 8; u++) xch[u*68 + lane] = v[u];
  __builtin_amdgcn_wave_barrier();
  { const float4* rp = (const float4*)(xch + p2*68 + u0*8);
    #pragma unroll
    for (int q = 0; q < 4; q++) {
      float4 t = rp[q];
      v[2*q]   = make_float2(t.x, t.y);
      v[2*q+1] = make_float2(t.z, t.w);
    } }
  dft8<S, false>(v);
}

__global__ void __launch_bounds__(256, 4)
k_fused(const float* __restrict__ mask, const float* __restrict__ prm,
        const float* __restrict__ sfx, const float* __restrict__ sfy,
        char* ws, float2* R1t, float2* Wg, __half2* T2, float* acc,
        float* out, int CH) {
  const int t = threadIdx.x, lane = t & 63, wv = t >> 6;
  const unsigned nblk = gridDim.x;
  unsigned* bcnt = (unsigned*)(ws + O_BAR);
  unsigned* bgen = (unsigned*)(ws + O_BAR + 64);
  unsigned ep = 0;
  __shared__ __align__(16) float2 lds[4*544];
  __shared__ __align__(16) float2 twt[512];
  __shared__ float FMt[241];
  build_twt(twt);
  if (t < 241) FMt[t] = (float)(((double)(t - 120)) / 100.0);
  float2* const xch = lds + wv*544;

  // ---------------- phase B1: setup (block 0) + row FFTs -------------------
  if (blockIdx.x == 0) {
    float*  sw  = (float*)lds;                 // scratch overlay (pre-FFT)
    float*  sxx = sw + 192; float* syy = sxx + 192; float* scw = syy + 192;
    double* so  = (double*)(sw + 768);
    int*    skp = (int*)(so + 176);
    if (t < 169) {
      float p = prm[t];
      float val = 1.f / (1.f + __expf(-8.f * p));
      float w = (val >= 0.001f) ? val : 0.f;
      double o = 0.0; float fx = 0.f, fy = 0.f;
      if (w > 0.f) {
        fx = sfx[t]; fy = sfy[t];
        double f2 = (double)fx*(double)fx + (double)fy*(double)fy;
        o = (double)w * sqrt((1.0 - 0.11390625 * f2) / (1.0 - 0.87890625 * f2));
      }
      sw[t] = w; so[t] = o; sxx[t] = fx; syy[t] = fy;
    }
    __syncthreads();
    if (t < 169) {                      // merge s with s'=(-fx,-fy): exact
      float w = sw[t];
      int keep = 0; float cw = w;
      if (w > 0.f) {
        float fx = sxx[t], fy = syy[t];
        int pr = -1;
        for (int s2 = 0; s2 < 169; s2++) {
          if (sw[s2] > 0.f && fabsf(sxx[s2] + fx) < 1e-5f
                           && fabsf(syy[s2] + fy) < 1e-5f) { pr = s2; break; }
        }
        if (pr < 0 || pr == t) keep = 1;
        else if (pr > t) { keep = 1; cw = w + sw[pr]; }
      }
      skp[t] = keep; scw[t] = cw;
    }
    __syncthreads();
    if (t == 0) {
      float* wsfw = (float*)ws;
      double Sden = 0.0; int c = 0;
      for (int s = 0; s < 169; s++) {
        Sden += so[s];                               // norm over ALL valid
        if (skp[s]) { wsfw[64+c] = scw[s]; wsfw[320+c] = sxx[s]; wsfw[576+c] = syy[s]; c++; }
      }
      ((int*)ws)[0] = c;
      wsfw[1] = (float)(1.0 / (262144.0 * 1.44 * Sden));  // 512^2 refold
    }
  }
  __syncthreads();                              // setup scratch dead; twt ready
  for (int rb = blockIdx.x; rb < 128; rb += nblk) {
    int y = rb * 4 + wv;
    float2 v[8];
    #pragma unroll
    for (int q = 0; q < 8; q++) v[q] = make_float2(mask[y*512 + 64*q + lane], 0.f);
    wfft512<-1, false>(v, lane, xch, twt);
    #pragma unroll
    for (int u = 0; u < 8; u++) {
      int k = (lane>>3) + 8*(lane&7) + 64*u;
      int beta = (k >= 392) ? (k - 392) : ((k <= 120) ? (k + 120) : -1);
      if (beta >= 0) R1t[beta*512 + y] = v[u];
    }
  }
  gbar(bcnt, bgen, nblk, ep);

  // ---------------- phase B2: col FFT -> W[alpha][beta] --------------------
  for (int jb = blockIdx.x; jb < 61; jb += nblk) {
    int j = jb * 4 + wv;                        // beta 0..243
    float2 v[8];
    #pragma unroll
    for (int q = 0; q < 8; q++)
      v[q] = (j < 241) ? R1t[j*512 + 64*q + lane] : make_float2(0.f, 0.f);
    wfft512<-1, false>(v, lane, xch, twt);
    if (j < 241) {
      #pragma unroll
      for (int u = 0; u < 8; u++) {
        int k = (lane>>3) + 8*(lane&7) + 64*u;
        int alpha = (k >= 392) ? (k - 392) : ((k <= 120) ? (k + 120) : -1);
        if (alpha >= 0) Wg[alpha*241 + j] = v[u];
      }
    }
  }
  gbar(bcnt, bgen, nblk, ep);

  const float* wsf = (const float*)ws;
  const int count = *(const int*)ws;
  int nb = (count + CH - 1) / CH;
  if (nb < 1) nb = 1;                           // count==0 still zero-fills acc
  for (int bi = 0; bi < nb; bi++) {
    const int base = bi * CH;
    int active = count - base;
    if (active > CH) active = CH;
    if (active < 0) active = 0;
    const int ntask = active * 31;

    // -------- phase C1: row IDFT of (W.*P)*sqrt(w)/512 -> T2 fp16 ---------
    for (int task = blockIdx.x; task < ntask; task += nblk) {
      int sic  = task / 31;
      int tile = task % 31;                    // 8 alphas/tile, 2 phases of 4
      int slot = base + sic;
      float fx = wsf[320 + slot], fy = wsf[576 + slot];
      float sqw = __fsqrt_rn(wsf[64 + slot]) * 0.001953125f;  // sqrt(w)/512
      #pragma unroll
      for (int ph = 0; ph < 2; ph++) {
        int alpha = tile*8 + ph*4 + wv;
        bool arow = (alpha < 241);
        float Gf = __fadd_rn(arow ? FMt[alpha] : 0.f, fy);
        float g2 = __fmul_rn(Gf, Gf);
        bool active_row = arow && (g2 <= 1.0f); // fl(G^2)>1 -> row all-zero
        float2 v[8];
        #pragma unroll
        for (int q = 0; q < 8; q++) v[q] = make_float2(0.f, 0.f);
        if (active_row) {
          #pragma unroll
          for (int q = 0; q < 4; q++) {        // n<241 -> q<4 only
            int n = 64*q + lane;
            if (n < 241) {
              float Ff = __fadd_rn(FMt[n], fx);
              float r2 = __fadd_rn(__fmul_rn(Ff, Ff), g2);  // np f32 semantics
              if (r2 <= 1.0f) {
                float num = fmaf(-0.11390625f, r2, 1.0f);
                float den = fmaf(-0.87890625f, r2, 1.0f);
                float P = __fsqrt_rn(__fsqrt_rn(__fdividef(num, den))) * sqw;
                float2 Wv = Wg[alpha*241 + n];
                v[q] = make_float2(P * Wv.x, P * Wv.y);
              }
            }
          }
          wfft512<1, true>(v, lane, xch, twt);
        }
        #pragma unroll
        for (int u = 0; u < 8; u++) {
          int xx = (lane>>3) + 8*(lane&7) + 64*u;
          xch[xx] = v[u];                      // zeros when inactive
        }
        __syncthreads();
        int colb = tile*8 + ph*4;
        if (colb < 244) {                      // tile30/ph1 would spill: skip
          #pragma unroll
          for (int r = 0; r < 2; r++) {
            int x = t + 256*r;
            union { __half2 h[4]; float4 f; } uu;
            #pragma unroll
            for (int wvi = 0; wvi < 4; wvi++) {
              float2 a = lds[wvi*544 + x];
              uu.h[wvi] = __floats2half2_rn(a.x, a.y);
            }
            // T2 layout [sic][x][col] (C2-read-coalesced, as in split vers.)
            *(float4*)(T2 + ((size_t)sic*512 + x)*244 + colb) = uu.f;
          }
        }
        __syncthreads();
      }
    }
    gbar(bcnt, bgen, nblk, ep);

    // -------- phase C2: col IDFT per source, acc += |AA'|^2 ---------------
    for (int unit = blockIdx.x; unit < 1024; unit += nblk) {
      int part = unit & 7;
      int x = (unit >> 3) * 4 + wv;
      float av[8] = {0.f,0.f,0.f,0.f,0.f,0.f,0.f,0.f};
      int sic = part;
      bool act = (sic < CH) && (base + sic < count);
      __half2 pv[4] = {{0.f,0.f},{0.f,0.f},{0.f,0.f},{0.f,0.f}};
      if (act) {
        const __half2* row = T2 + ((size_t)sic*512 + x)*244;
        #pragma unroll
        for (int q = 0; q < 4; q++) {
          int n = 64*q + lane;
          pv[q] = (n < 241) ? row[n] : __half2{0.f, 0.f};
        }
      }
      while (act) {
        float2 v[8];
        #pragma unroll
        for (int q = 0; q < 4; q++) v[q] = __half22float2(pv[q]);
        #pragma unroll
        for (int q = 4; q < 8; q++) v[q] = make_float2(0.f, 0.f);
        int nsic = sic + SPLIT;
        act = (nsic < CH) && (base + nsic < count);
        if (act) {                             // prefetch across the FFT
          const __half2* row = T2 + ((size_t)nsic*512 + x)*244;
          #pragma unroll
          for (int q = 0; q < 4; q++) {
            int n = 64*q + lane;
            pv[q] = (n < 241) ? row[n] : __half2{0.f, 0.f};
          }
        }
        wfft512<1, true>(v, lane, xch, twt);
        #pragma unroll
        for (int u = 0; u < 8; u++)
          av[u] += fmaf(v[u].x, v[u].x, v[u].y*v[u].y);
        sic = nsic;
      }
      float* a = acc + ((size_t)part << 18) + (size_t)x * 512;
      int y0 = (lane>>3) + 8*(lane&7);
      if (bi == 0) {
        #pragma unroll
        for (int u = 0; u < 8; u++) a[y0 + 64*u] = av[u];
      } else {
        #pragma unroll
        for (int u = 0; u < 8; u++) a[y0 + 64*u] += av[u];
      }
    }
    gbar(bcnt, bgen, nblk, ep);
  }

  // ---------------- phase D: transpose, scale, doses, resist ---------------
  {
    float scale = wsf[1];
    float (*tile2)[33] = reinterpret_cast<float(*)[33]>((float*)lds);
    const float dd[3] = {0.9604f, 1.0f, 1.0404f};
    int tx = t & 31, ty0 = t >> 5;
    for (int tb = blockIdx.x; tb < 256; tb += nblk) {
      int x0 = (tb & 15) * 32, y0 = (tb >> 4) * 32;
      #pragma unroll
      for (int r = 0; r < 4; r++) {
        int i = ty0 + 8*r;
        const float* ap = acc + (size_t)(x0 + i)*512 + y0 + tx;
        float s = 0.f;
        #pragma unroll
        for (int p = 0; p < SPLIT; p++) s += ap[(size_t)p << 18];
        tile2[i][tx] = s;
      }
      __syncthreads();
      #pragma unroll
      for (int r = 0; r < 4; r++) {
        int yy = ty0 + 8*r;
        float I = scale * tile2[tx][yy];
        int o = (y0 + yy)*512 + x0 + tx;
        #pragma unroll
        for (int d = 0; d < 3; d++) {
          float Ik = dd[d] * I;
          out[(size_t)d*262144 + o] = Ik;
          out[(size_t)(3+d)*262144 + o] = 1.f / (1.f + __expf(-30.f*(Ik - 0.225f)));
        }
      }
      __syncthreads();
    }
  }
}

extern "C" void kernel_launch(void* const* d_in, const int* in_sizes, int n_in,
                              void* d_out, int out_size, void* d_ws, size_t ws_size,
                              hipStream_t stream) {
  (void)in_sizes; (void)n_in; (void)out_size;
  const float* mask = (const float*)d_in[0];
  const float* prm  = (const float*)d_in[1];
  const float* sfx  = (const float*)d_in[2];
  const float* sfy  = (const float*)d_in[3];
  float* out = (float*)d_out;
  char*  ws  = (char*)d_ws;

  float*   acc = (float*)(ws + O_ACC);
  float2*  Wg  = (float2*)(ws + O_WIN);
  float2*  R1t = (float2*)(ws + O_R1);
  __half2* T2  = (__half2*)(ws + O_T2);

  size_t avail = (ws_size > O_T2) ? (ws_size - O_T2) : 0;
  int CH = (int)(avail / SLOT_BYTES);
  if (CH > 169) CH = 169;
  if (CH < 1)   CH = 1;

  // Cooperative grid size: occupancy-derived (cached), capped at 1024 units.
  static int grid_blocks = 0;
  if (grid_blocks == 0) {
    int nbk = 0;
    if (hipOccupancyMaxActiveBlocksPerMultiprocessor(
            &nbk, (const void*)k_fused, 256, 0) != hipSuccess || nbk < 1)
      nbk = 1;
    int ncu = 256;
    hipDeviceProp_t prop;
    int dev = 0;
    if (hipGetDevice(&dev) == hipSuccess &&
        hipGetDeviceProperties(&prop, dev) == hipSuccess &&
        prop.multiProcessorCount > 0)
      ncu = prop.multiProcessorCount;
    long g = (long)nbk * (long)ncu;
    if (g > 1024) g = 1024;
    if (g < 1) g = 1;
    grid_blocks = (int)g;
  }

  // Zero the barrier counters (captured; ws is re-poisoned every iteration).
  hipMemsetAsync(ws + O_BAR, 0, 128, stream);

  void* args[] = { (void*)&mask, (void*)&prm, (void*)&sfx, (void*)&sfy,
                   (void*)&ws, (void*)&R1t, (void*)&Wg, (void*)&T2,
                   (void*)&acc, (void*)&out, (void*)&CH };
  hipLaunchCooperativeKernel((const void*)k_fused, dim3(grid_blocks), dim3(256),
                             args, 0, stream);
}

// Round 3
// 249.680 us; speedup vs baseline: 1.4001x; 1.2825x over previous
//
#include <hip/hip_runtime.h>
#include <hip/hip_fp16.h>

// ---------------------------------------------------------------------------
// Abbe lithography forward — single cooperative-launched kernel with a
// TWO-LEVEL TREE grid-barrier.
// R1: cg::grid.sync ~95us/sync. R2: flat atomic barrier also ~95us/sync —
// root cause: 1024-way same-cacheline contention (and R2's cnt/gen shared a
// 128B line, so 1023 spin-loads serialized every arrival RMW).
// R3: 32 groups x 32 blocks; per-group cnt/gen on separate 256B-spaced
// lines; 32 leaders arrive at root; release fans out root->group->block.
// Max same-line contention: 32 (was 1024), spin lines disjoint from
// counter lines.
// Math identical to the verified 5-kernel version: doses factor out
// (I(d)=d^2 I(1)); shift phases cancel in |AA|^2; weight cancels against
// norm_I; +/- source pairs merged (exact).
// Phases (gbar between):
//   B1: block0 setup -> ws hdr; rows FFT of mask, keep 241 cols -> R1t
//   B2: col FFT, keep 241 rows -> W[alpha][beta]
//   C1: per (source,tile) row IDFT of (W.*P)*sqrt(w)/512 -> T2 fp16
//   C2: per source col IDFT, acc[part][x][y] = sum |AA'|^2
//   D : transpose 32x32 tiles, scale, 3 doses, resist sigmoid
// FFT-512: radix-8, 3 stages, one wave per FFT, wave-level sync only.
// Barrier region in ws[+4096 .. +28672); zeroed by captured hipMemsetAsync.
// ---------------------------------------------------------------------------

#define SPLIT 8

static const size_t O_BAR  = 4096;                 // 24KB barrier region
//   gcnt[g] @ O_BAR + g*256        (g < 32)
//   ggen[g] @ O_BAR + 8192 + g*256
//   rcnt    @ O_BAR + 16384
//   rgen    @ O_BAR + 16640
static const size_t O_ACC  = 32768;                // SPLIT*512*512*f32
static const size_t ACC_BYTES = (size_t)SPLIT * 512 * 512 * 4;
static const size_t O_WIN  = O_ACC + ACC_BYTES;
static const size_t O_R1   = O_WIN + 464896;
static const size_t O_T2   = O_R1 + 987136;
static const size_t SLOT_BYTES = (size_t)512 * 244 * 4;  // half2 slots

__device__ inline float2 cadd(float2 a, float2 b){ return make_float2(a.x+b.x, a.y+b.y); }
__device__ inline float2 csub(float2 a, float2 b){ return make_float2(a.x-b.x, a.y-b.y); }
__device__ inline float2 cmul(float2 a, float2 b){
  return make_float2(fmaf(a.x, b.x, -(a.y*b.y)), fmaf(a.x, b.y, a.y*b.x));
}
__device__ inline float2 twsgn(float2 t, int S) {
  return make_float2(t.x, (S > 0) ? t.y : -t.y);
}

// Two-level tree grid-barrier. nblk must be a multiple of 32.
// One RMW per block on its group line; leaders RMW the root line; release
// fans out root->group. Spin lines never alias arrival-counter lines.
__device__ inline void gbar(char* bar, unsigned nblk, unsigned& ep) {
  __syncthreads();
  ep++;
  if (threadIdx.x == 0) {
    const unsigned target = ep;
    const unsigned g    = blockIdx.x >> 5;
    const unsigned ngrp = nblk >> 5;
    unsigned* gcnt = (unsigned*)(bar + (size_t)g * 256);
    unsigned* ggen = (unsigned*)(bar + 8192 + (size_t)g * 256);
    unsigned* rcnt = (unsigned*)(bar + 16384);
    unsigned* rgen = (unsigned*)(bar + 16640);
    __threadfence();                           // release: drain my writes
    unsigned old = __hip_atomic_fetch_add(gcnt, 1u, __ATOMIC_RELAXED,
                                          __HIP_MEMORY_SCOPE_AGENT);
    if (old == 31u) {                          // group leader
      __hip_atomic_store(gcnt, 0u, __ATOMIC_RELAXED, __HIP_MEMORY_SCOPE_AGENT);
      unsigned r = __hip_atomic_fetch_add(rcnt, 1u, __ATOMIC_RELAXED,
                                          __HIP_MEMORY_SCOPE_AGENT);
      if (r == ngrp - 1u) {                    // last group: release root
        __hip_atomic_store(rcnt, 0u, __ATOMIC_RELAXED, __HIP_MEMORY_SCOPE_AGENT);
        __hip_atomic_store(rgen, target, __ATOMIC_RELEASE,
                           __HIP_MEMORY_SCOPE_AGENT);
      } else {
        while (__hip_atomic_load(rgen, __ATOMIC_RELAXED,
                                 __HIP_MEMORY_SCOPE_AGENT) < target)
          __builtin_amdgcn_s_sleep(2);
      }
      __hip_atomic_store(ggen, target, __ATOMIC_RELEASE,
                         __HIP_MEMORY_SCOPE_AGENT);
    } else {
      while (__hip_atomic_load(ggen, __ATOMIC_RELAXED,
                               __HIP_MEMORY_SCOPE_AGENT) < target)
        __builtin_amdgcn_s_sleep(2);
    }
    __threadfence();                           // acquire: invalidate caches
  }
  __syncthreads();
}

// Per-block twiddle table exp(+2*pi*i*k/512), f64-built (256-thread blocks).
__device__ inline void build_twt(float2* twt) {
  for (int k = (int)threadIdx.x; k < 512; k += 256) {
    double a = 6.283185307179586476925286766559 * (double)k / 512.0;
    twt[k] = make_float2((float)cos(a), (float)sin(a));
  }
}

// Radix-8 butterfly. If ZTOP, v[4..7] are known zero (skips first add level).
template<int S, bool ZTOP>
__device__ inline void dft8(float2 v[8]) {
  const float sg = (float)S;
  const float C7 = 0.7071067811865476f;
  float2 t0, t1, t2, t3, t4, t5, t6, t7;
  if (ZTOP) {
    t0 = v[0]; t4 = v[0];
    t1 = v[1]; t5 = v[1];
    t2 = v[2]; t6 = v[2];
    t3 = v[3]; t7 = v[3];
  } else {
    t0=cadd(v[0],v[4]); t4=csub(v[0],v[4]);
    t1=cadd(v[1],v[5]); t5=csub(v[1],v[5]);
    t2=cadd(v[2],v[6]); t6=csub(v[2],v[6]);
    t3=cadd(v[3],v[7]); t7=csub(v[3],v[7]);
  }
  t5 = make_float2(C7*(t5.x - sg*t5.y), C7*(t5.y + sg*t5.x));
  t6 = make_float2(-sg*t6.y, sg*t6.x);
  t7 = make_float2(C7*(-t7.x - sg*t7.y), C7*(sg*t7.x - t7.y));
  float2 u0=cadd(t0,t2), u2=csub(t0,t2);
  float2 u1=cadd(t1,t3), u3=csub(t1,t3);
  u3 = make_float2(-sg*u3.y, sg*u3.x);
  float2 u4=cadd(t4,t6), u6=csub(t4,t6);
  float2 u5=cadd(t5,t7), u7=csub(t5,t7);
  u7 = make_float2(-sg*u7.y, sg*u7.x);
  v[0]=cadd(u0,u1); v[4]=csub(u0,u1);
  v[2]=cadd(u2,u3); v[6]=csub(u2,u3);
  v[1]=cadd(u4,u5); v[5]=csub(u4,u5);
  v[3]=cadd(u6,u7); v[7]=csub(u6,u7);
}

// One-wave FFT-512; xch = per-wave float2[544] (16B aligned). Wave-sync only.
template<int S, bool ZTOP>
__device__ inline void wfft512(float2 v[8], int lane, float2* xch,
                               const float2* twt) {
  const int p2 = lane & 7, u0 = lane >> 3;
  dft8<S, ZTOP>(v);
  { float2 t1 = twsgn(twt[lane], S), acc = t1;
    v[1] = cmul(v[1], acc);
    #pragma unroll
    for (int u = 2; u < 8; u++) { acc = cmul(acc, t1); v[u] = cmul(v[u], acc); } }
  __builtin_amdgcn_wave_barrier();
  #pragma unroll
  for (int u = 0; u < 8; u++) xch[u*68 + p2*8 + u0] = v[u];
  __builtin_amdgcn_wave_barrier();
  { const float4* rp = (const float4*)(xch + u0*68 + p2*8);
    #pragma unroll
    for (int q = 0; q < 4; q++) {
      float4 t = rp[q];
      v[2*q]   = make_float2(t.x, t.y);
      v[2*q+1] = make_float2(t.z, t.w);
    } }
  dft8<S, false>(v);
  { float2 t1 = twsgn(twt[p2 << 3], S), acc = t1;
    v[1] = cmul(v[1], acc);
    #pragma unroll
    for (int u = 2; u < 8; u++) { acc = cmul(acc, t1); v[u] = cmul(v[u], acc); } }
  __builtin_amdgcn_wave_barrier();
  #pragma unroll
  for (int u = 0; u < 8; u++) xch[u*68 + lane] = v[u];
  __builtin_amdgcn_wave_barrier();
  { const float4* rp = (const float4*)(xch + p2*68 + u0*8);
    #pragma unroll
    for (int q = 0; q < 4; q++) {
      float4 t = rp[q];
      v[2*q]   = make_float2(t.x, t.y);
      v[2*q+1] = make_float2(t.z, t.w);
    } }
  dft8<S, false>(v);
}

__global__ void __launch_bounds__(256, 4)
k_fused(const float* __restrict__ mask, const float* __restrict__ prm,
        const float* __restrict__ sfx, const float* __restrict__ sfy,
        char* ws, float2* R1t, float2* Wg, __half2* T2, float* acc,
        float* out, int CH) {
  const int t = threadIdx.x, lane = t & 63, wv = t >> 6;
  const unsigned nblk = gridDim.x;
  char* bar = ws + O_BAR;
  unsigned ep = 0;
  __shared__ __align__(16) float2 lds[4*544];
  __shared__ __align__(16) float2 twt[512];
  __shared__ float FMt[241];
  build_twt(twt);
  if (t < 241) FMt[t] = (float)(((double)(t - 120)) / 100.0);
  float2* const xch = lds + wv*544;

  // ---------------- phase B1: setup (block 0) + row FFTs -------------------
  if (blockIdx.x == 0) {
    float*  sw  = (float*)lds;                 // scratch overlay (pre-FFT)
    float*  sxx = sw + 192; float* syy = sxx + 192; float* scw = syy + 192;
    double* so  = (double*)(sw + 768);
    int*    skp = (int*)(so + 176);
    if (t < 169) {
      float p = prm[t];
      float val = 1.f / (1.f + __expf(-8.f * p));
      float w = (val >= 0.001f) ? val : 0.f;
      double o = 0.0; float fx = 0.f, fy = 0.f;
      if (w > 0.f) {
        fx = sfx[t]; fy = sfy[t];
        double f2 = (double)fx*(double)fx + (double)fy*(double)fy;
        o = (double)w * sqrt((1.0 - 0.11390625 * f2) / (1.0 - 0.87890625 * f2));
      }
      sw[t] = w; so[t] = o; sxx[t] = fx; syy[t] = fy;
    }
    __syncthreads();
    if (t < 169) {                      // merge s with s'=(-fx,-fy): exact
      float w = sw[t];
      int keep = 0; float cw = w;
      if (w > 0.f) {
        float fx = sxx[t], fy = syy[t];
        int pr = -1;
        for (int s2 = 0; s2 < 169; s2++) {
          if (sw[s2] > 0.f && fabsf(sxx[s2] + fx) < 1e-5f
                           && fabsf(syy[s2] + fy) < 1e-5f) { pr = s2; break; }
        }
        if (pr < 0 || pr == t) keep = 1;
        else if (pr > t) { keep = 1; cw = w + sw[pr]; }
      }
      skp[t] = keep; scw[t] = cw;
    }
    __syncthreads();
    if (t == 0) {
      float* wsfw = (float*)ws;
      double Sden = 0.0; int c = 0;
      for (int s = 0; s < 169; s++) {
        Sden += so[s];                               // norm over ALL valid
        if (skp[s]) { wsfw[64+c] = scw[s]; wsfw[320+c] = sxx[s]; wsfw[576+c] = syy[s]; c++; }
      }
      ((int*)ws)[0] = c;
      wsfw[1] = (float)(1.0 / (262144.0 * 1.44 * Sden));  // 512^2 refold
    }
  }
  __syncthreads();                              // setup scratch dead; twt ready
  for (int rb = blockIdx.x; rb < 128; rb += nblk) {
    int y = rb * 4 + wv;
    float2 v[8];
    #pragma unroll
    for (int q = 0; q < 8; q++) v[q] = make_float2(mask[y*512 + 64*q + lane], 0.f);
    wfft512<-1, false>(v, lane, xch, twt);
    #pragma unroll
    for (int u = 0; u < 8; u++) {
      int k = (lane>>3) + 8*(lane&7) + 64*u;
      int beta = (k >= 392) ? (k - 392) : ((k <= 120) ? (k + 120) : -1);
      if (beta >= 0) R1t[beta*512 + y] = v[u];
    }
  }
  gbar(bar, nblk, ep);

  // ---------------- phase B2: col FFT -> W[alpha][beta] --------------------
  for (int jb = blockIdx.x; jb < 61; jb += nblk) {
    int j = jb * 4 + wv;                        // beta 0..243
    float2 v[8];
    #pragma unroll
    for (int q = 0; q < 8; q++)
      v[q] = (j < 241) ? R1t[j*512 + 64*q + lane] : make_float2(0.f, 0.f);
    wfft512<-1, false>(v, lane, xch, twt);
    if (j < 241) {
      #pragma unroll
      for (int u = 0; u < 8; u++) {
        int k = (lane>>3) + 8*(lane&7) + 64*u;
        int alpha = (k >= 392) ? (k - 392) : ((k <= 120) ? (k + 120) : -1);
        if (alpha >= 0) Wg[alpha*241 + j] = v[u];
      }
    }
  }
  gbar(bar, nblk, ep);

  const float* wsf = (const float*)ws;
  const int count = *(const int*)ws;
  int nb = (count + CH - 1) / CH;
  if (nb < 1) nb = 1;                           // count==0 still zero-fills acc
  for (int bi = 0; bi < nb; bi++) {
    const int base = bi * CH;
    int active = count - base;
    if (active > CH) active = CH;
    if (active < 0) active = 0;
    const int ntask = active * 31;

    // -------- phase C1: row IDFT of (W.*P)*sqrt(w)/512 -> T2 fp16 ---------
    for (int task = blockIdx.x; task < ntask; task += nblk) {
      int sic  = task / 31;
      int tile = task % 31;                    // 8 alphas/tile, 2 phases of 4
      int slot = base + sic;
      float fx = wsf[320 + slot], fy = wsf[576 + slot];
      float sqw = __fsqrt_rn(wsf[64 + slot]) * 0.001953125f;  // sqrt(w)/512
      #pragma unroll
      for (int ph = 0; ph < 2; ph++) {
        int alpha = tile*8 + ph*4 + wv;
        bool arow = (alpha < 241);
        float Gf = __fadd_rn(arow ? FMt[alpha] : 0.f, fy);
        float g2 = __fmul_rn(Gf, Gf);
        bool active_row = arow && (g2 <= 1.0f); // fl(G^2)>1 -> row all-zero
        float2 v[8];
        #pragma unroll
        for (int q = 0; q < 8; q++) v[q] = make_float2(0.f, 0.f);
        if (active_row) {
          #pragma unroll
          for (int q = 0; q < 4; q++) {        // n<241 -> q<4 only
            int n = 64*q + lane;
            if (n < 241) {
              float Ff = __fadd_rn(FMt[n], fx);
              float r2 = __fadd_rn(__fmul_rn(Ff, Ff), g2);  // np f32 semantics
              if (r2 <= 1.0f) {
                float num = fmaf(-0.11390625f, r2, 1.0f);
                float den = fmaf(-0.87890625f, r2, 1.0f);
                float P = __fsqrt_rn(__fsqrt_rn(__fdividef(num, den))) * sqw;
                float2 Wv = Wg[alpha*241 + n];
                v[q] = make_float2(P * Wv.x, P * Wv.y);
              }
            }
          }
          wfft512<1, true>(v, lane, xch, twt);
        }
        #pragma unroll
        for (int u = 0; u < 8; u++) {
          int xx = (lane>>3) + 8*(lane&7) + 64*u;
          xch[xx] = v[u];                      // zeros when inactive
        }
        __syncthreads();
        int colb = tile*8 + ph*4;
        if (colb < 244) {                      // tile30/ph1 would spill: skip
          #pragma unroll
          for (int r = 0; r < 2; r++) {
            int x = t + 256*r;
            union { __half2 h[4]; float4 f; } uu;
            #pragma unroll
            for (int wvi = 0; wvi < 4; wvi++) {
              float2 a = lds[wvi*544 + x];
              uu.h[wvi] = __floats2half2_rn(a.x, a.y);
            }
            // T2 layout [sic][x][col] (C2-read-coalesced)
            *(float4*)(T2 + ((size_t)sic*512 + x)*244 + colb) = uu.f;
          }
        }
        __syncthreads();
      }
    }
    gbar(bar, nblk, ep);

    // -------- phase C2: col IDFT per source, acc += |AA'|^2 ---------------
    for (int unit = blockIdx.x; unit < 1024; unit += nblk) {
      int part = unit & 7;
      int x = (unit >> 3) * 4 + wv;
      float av[8] = {0.f,0.f,0.f,0.f,0.f,0.f,0.f,0.f};
      int sic = part;
      bool act = (sic < CH) && (base + sic < count);
      __half2 pv[4] = {{0.f,0.f},{0.f,0.f},{0.f,0.f},{0.f,0.f}};
      if (act) {
        const __half2* row = T2 + ((size_t)sic*512 + x)*244;
        #pragma unroll
        for (int q = 0; q < 4; q++) {
          int n = 64*q + lane;
          pv[q] = (n < 241) ? row[n] : __half2{0.f, 0.f};
        }
      }
      while (act) {
        float2 v[8];
        #pragma unroll
        for (int q = 0; q < 4; q++) v[q] = __half22float2(pv[q]);
        #pragma unroll
        for (int q = 4; q < 8; q++) v[q] = make_float2(0.f, 0.f);
        int nsic = sic + SPLIT;
        act = (nsic < CH) && (base + nsic < count);
        if (act) {                             // prefetch across the FFT
          const __half2* row = T2 + ((size_t)nsic*512 + x)*244;
          #pragma unroll
          for (int q = 0; q < 4; q++) {
            int n = 64*q + lane;
            pv[q] = (n < 241) ? row[n] : __half2{0.f, 0.f};
          }
        }
        wfft512<1, true>(v, lane, xch, twt);
        #pragma unroll
        for (int u = 0; u < 8; u++)
          av[u] += fmaf(v[u].x, v[u].x, v[u].y*v[u].y);
        sic = nsic;
      }
      float* a = acc + ((size_t)part << 18) + (size_t)x * 512;
      int y0 = (lane>>3) + 8*(lane&7);
      if (bi == 0) {
        #pragma unroll
        for (int u = 0; u < 8; u++) a[y0 + 64*u] = av[u];
      } else {
        #pragma unroll
        for (int u = 0; u < 8; u++) a[y0 + 64*u] += av[u];
      }
    }
    gbar(bar, nblk, ep);
  }

  // ---------------- phase D: transpose, scale, doses, resist ---------------
  {
    float scale = wsf[1];
    float (*tile2)[33] = reinterpret_cast<float(*)[33]>((float*)lds);
    const float dd[3] = {0.9604f, 1.0f, 1.0404f};
    int tx = t & 31, ty0 = t >> 5;
    for (int tb = blockIdx.x; tb < 256; tb += nblk) {
      int x0 = (tb & 15) * 32, y0 = (tb >> 4) * 32;
      #pragma unroll
      for (int r = 0; r < 4; r++) {
        int i = ty0 + 8*r;
        const float* ap = acc + (size_t)(x0 + i)*512 + y0 + tx;
        float s = 0.f;
        #pragma unroll
        for (int p = 0; p < SPLIT; p++) s += ap[(size_t)p << 18];
        tile2[i][tx] = s;
      }
      __syncthreads();
      #pragma unroll
      for (int r = 0; r < 4; r++) {
        int yy = ty0 + 8*r;
        float I = scale * tile2[tx][yy];
        int o = (y0 + yy)*512 + x0 + tx;
        #pragma unroll
        for (int d = 0; d < 3; d++) {
          float Ik = dd[d] * I;
          out[(size_t)d*262144 + o] = Ik;
          out[(size_t)(3+d)*262144 + o] = 1.f / (1.f + __expf(-30.f*(Ik - 0.225f)));
        }
      }
      __syncthreads();
    }
  }
}

extern "C" void kernel_launch(void* const* d_in, const int* in_sizes, int n_in,
                              void* d_out, int out_size, void* d_ws, size_t ws_size,
                              hipStream_t stream) {
  (void)in_sizes; (void)n_in; (void)out_size;
  const float* mask = (const float*)d_in[0];
  const float* prm  = (const float*)d_in[1];
  const float* sfx  = (const float*)d_in[2];
  const float* sfy  = (const float*)d_in[3];
  float* out = (float*)d_out;
  char*  ws  = (char*)d_ws;

  float*   acc = (float*)(ws + O_ACC);
  float2*  Wg  = (float2*)(ws + O_WIN);
  float2*  R1t = (float2*)(ws + O_R1);
  __half2* T2  = (__half2*)(ws + O_T2);

  size_t avail = (ws_size > O_T2) ? (ws_size - O_T2) : 0;
  int CH = (int)(avail / SLOT_BYTES);
  if (CH > 169) CH = 169;
  if (CH < 1)   CH = 1;

  // Cooperative grid: occupancy-derived, multiple of 32 (tree groups),
  // capped at 1024.
  static int grid_blocks = 0;
  if (grid_blocks == 0) {
    int nbk = 0;
    if (hipOccupancyMaxActiveBlocksPerMultiprocessor(
            &nbk, (const void*)k_fused, 256, 0) != hipSuccess || nbk < 1)
      nbk = 1;
    int ncu = 256;
    hipDeviceProp_t prop;
    int dev = 0;
    if (hipGetDevice(&dev) == hipSuccess &&
        hipGetDeviceProperties(&prop, dev) == hipSuccess &&
        prop.multiProcessorCount > 0)
      ncu = prop.multiProcessorCount;
    long g = (long)nbk * (long)ncu;
    if (g > 1024) g = 1024;
    g &= ~31L;                                  // multiple of 32 for the tree
    if (g < 32) g = 32;
    grid_blocks = (int)g;
  }

  // Zero the barrier region (captured; ws is re-poisoned every iteration).
  hipMemsetAsync(ws + O_BAR, 0, 24576, stream);

  void* args[] = { (void*)&mask, (void*)&prm, (void*)&sfx, (void*)&sfy,
                   (void*)&ws, (void*)&R1t, (void*)&Wg, (void*)&T2,
                   (void*)&acc, (void*)&out, (void*)&CH };
  hipLaunchCooperativeKernel((const void*)k_fused, dim3(grid_blocks), dim3(256),
                             args, 0, stream);
}

// Round 4
// 175.059 us; speedup vs baseline: 1.9970x; 1.4263x over previous
//
#include <hip/hip_runtime.h>
#include <hip/hip_fp16.h>

// ---------------------------------------------------------------------------
// Abbe lithography forward — single cooperative-launched kernel, FENCE-FREE
// tree grid-barrier + system-scope (sc0 sc1) cross-phase data.
// History: cg::grid.sync ~95us/sync (R1); flat atomic w/ threadfence ~95us
// (R2); tree w/ threadfence ~60us (R3). The ~60us invariant = per-block
// __threadfence -> buffer_wbl2/buffer_inv (whole-L2 writeback/inv), ~128
// serialized cache-maintenance ops per XCD-L2 per barrier.
// R4: NO fences. All cross-phase arrays (R1t, Wg, T2, acc, ws hdr) are
// accessed via relaxed SYSTEM-scope atomics (sc0 sc1: bypass L1/L2, live at
// the IF$ coherence point). Barrier = syncthreads + s_waitcnt vmcnt(0) +
// relaxed system-scope tree arrival/spin. vmcnt(0) retires write-through
// stores only when they reach the coherence point -> visibility w/o wbl2.
// Math identical to the verified 5-kernel version (absmax 0.00390625).
// Phases: B1 row FFT (+block0 setup) -> bar -> B2 col FFT -> bar ->
//         C1 row IDFT -> bar -> C2 col IDFT+|.|^2 -> bar -> D finalize.
// FFT-512: radix-8, 3 stages, one wave per FFT, wave-level sync only.
// ---------------------------------------------------------------------------

#define SPLIT 8

static const size_t O_BAR  = 4096;                 // 24KB barrier region
//   gcnt[g] @ O_BAR + g*256        (g < 32)
//   ggen[g] @ O_BAR + 8192 + g*256
//   rcnt    @ O_BAR + 16384
//   rgen    @ O_BAR + 16640
static const size_t O_ACC  = 32768;                // SPLIT*512*512*f32
static const size_t ACC_BYTES = (size_t)SPLIT * 512 * 512 * 4;
static const size_t O_WIN  = O_ACC + ACC_BYTES;
static const size_t O_R1   = O_WIN + 464896;
static const size_t O_T2   = O_R1 + 987136;
static const size_t SLOT_BYTES = (size_t)512 * 244 * 4;  // half2 slots

// ---- system-scope (coherence-point) load/store helpers --------------------
__device__ inline void st_sys_f(float* p, float v) {
  __hip_atomic_store((unsigned*)p, __float_as_uint(v),
                     __ATOMIC_RELAXED, __HIP_MEMORY_SCOPE_SYSTEM);
}
__device__ inline float ld_sys_f(const float* p) {
  return __uint_as_float(__hip_atomic_load((const unsigned*)p,
                     __ATOMIC_RELAXED, __HIP_MEMORY_SCOPE_SYSTEM));
}
__device__ inline void st_sys_i(int* p, int v) {
  __hip_atomic_store(p, v, __ATOMIC_RELAXED, __HIP_MEMORY_SCOPE_SYSTEM);
}
__device__ inline int ld_sys_i(const int* p) {
  return __hip_atomic_load(p, __ATOMIC_RELAXED, __HIP_MEMORY_SCOPE_SYSTEM);
}
__device__ inline void st_sys_f2(float2* p, float2 v) {
  union { float2 f; unsigned long long u; } c; c.f = v;
  __hip_atomic_store((unsigned long long*)p, c.u,
                     __ATOMIC_RELAXED, __HIP_MEMORY_SCOPE_SYSTEM);
}
__device__ inline float2 ld_sys_f2(const float2* p) {
  union { unsigned long long u; float2 f; } c;
  c.u = __hip_atomic_load((const unsigned long long*)p,
                     __ATOMIC_RELAXED, __HIP_MEMORY_SCOPE_SYSTEM);
  return c.f;
}
__device__ inline void st_sys_f4(void* p, float4 v) {
  union { float2 f; unsigned long long u; } a, b;
  a.f = make_float2(v.x, v.y); b.f = make_float2(v.z, v.w);
  unsigned long long* q = (unsigned long long*)p;
  __hip_atomic_store(q,     a.u, __ATOMIC_RELAXED, __HIP_MEMORY_SCOPE_SYSTEM);
  __hip_atomic_store(q + 1, b.u, __ATOMIC_RELAXED, __HIP_MEMORY_SCOPE_SYSTEM);
}
__device__ inline __half2 ld_sys_h2(const __half2* p) {
  union { unsigned u; __half2 h; } c;
  c.u = __hip_atomic_load((const unsigned*)p,
                     __ATOMIC_RELAXED, __HIP_MEMORY_SCOPE_SYSTEM);
  return c.h;
}

__device__ inline float2 cadd(float2 a, float2 b){ return make_float2(a.x+b.x, a.y+b.y); }
__device__ inline float2 csub(float2 a, float2 b){ return make_float2(a.x-b.x, a.y-b.y); }
__device__ inline float2 cmul(float2 a, float2 b){
  return make_float2(fmaf(a.x, b.x, -(a.y*b.y)), fmaf(a.x, b.y, a.y*b.x));
}
__device__ inline float2 twsgn(float2 t, int S) {
  return make_float2(t.x, (S > 0) ? t.y : -t.y);
}

// Fence-free two-level tree grid-barrier (nblk multiple of 32).
// All counters/gens at system scope (coherence point). No wbl2/inv: cross-
// phase data is itself system-scope, vmcnt(0) = stores at coherence point.
__device__ inline void gbar(char* bar, unsigned nblk, unsigned& ep) {
  __syncthreads();                 // compiler emits vmcnt(0) before s_barrier
  ep++;
  if (threadIdx.x == 0) {
    const unsigned target = ep;
    const unsigned g    = blockIdx.x >> 5;
    const unsigned ngrp = nblk >> 5;
    unsigned* gcnt = (unsigned*)(bar + (size_t)g * 256);
    unsigned* ggen = (unsigned*)(bar + 8192 + (size_t)g * 256);
    unsigned* rcnt = (unsigned*)(bar + 16384);
    unsigned* rgen = (unsigned*)(bar + 16640);
    asm volatile("s_waitcnt vmcnt(0)" ::: "memory");
    unsigned old = __hip_atomic_fetch_add(gcnt, 1u, __ATOMIC_RELAXED,
                                          __HIP_MEMORY_SCOPE_SYSTEM);
    if (old == 31u) {                          // group leader
      __hip_atomic_store(gcnt, 0u, __ATOMIC_RELAXED, __HIP_MEMORY_SCOPE_SYSTEM);
      unsigned r = __hip_atomic_fetch_add(rcnt, 1u, __ATOMIC_RELAXED,
                                          __HIP_MEMORY_SCOPE_SYSTEM);
      if (r == ngrp - 1u) {                    // last group: release root
        __hip_atomic_store(rcnt, 0u, __ATOMIC_RELAXED, __HIP_MEMORY_SCOPE_SYSTEM);
        __hip_atomic_store(rgen, target, __ATOMIC_RELAXED,
                           __HIP_MEMORY_SCOPE_SYSTEM);
      } else {
        while (__hip_atomic_load(rgen, __ATOMIC_RELAXED,
                                 __HIP_MEMORY_SCOPE_SYSTEM) < target)
          __builtin_amdgcn_s_sleep(2);
      }
      __hip_atomic_store(ggen, target, __ATOMIC_RELAXED,
                         __HIP_MEMORY_SCOPE_SYSTEM);
    } else {
      while (__hip_atomic_load(ggen, __ATOMIC_RELAXED,
                               __HIP_MEMORY_SCOPE_SYSTEM) < target)
        __builtin_amdgcn_s_sleep(4);
    }
  }
  __syncthreads();
}

// Per-block twiddle table exp(+2*pi*i*k/512), f64-built (256-thread blocks).
__device__ inline void build_twt(float2* twt) {
  for (int k = (int)threadIdx.x; k < 512; k += 256) {
    double a = 6.283185307179586476925286766559 * (double)k / 512.0;
    twt[k] = make_float2((float)cos(a), (float)sin(a));
  }
}

// Radix-8 butterfly. If ZTOP, v[4..7] are known zero (skips first add level).
template<int S, bool ZTOP>
__device__ inline void dft8(float2 v[8]) {
  const float sg = (float)S;
  const float C7 = 0.7071067811865476f;
  float2 t0, t1, t2, t3, t4, t5, t6, t7;
  if (ZTOP) {
    t0 = v[0]; t4 = v[0];
    t1 = v[1]; t5 = v[1];
    t2 = v[2]; t6 = v[2];
    t3 = v[3]; t7 = v[3];
  } else {
    t0=cadd(v[0],v[4]); t4=csub(v[0],v[4]);
    t1=cadd(v[1],v[5]); t5=csub(v[1],v[5]);
    t2=cadd(v[2],v[6]); t6=csub(v[2],v[6]);
    t3=cadd(v[3],v[7]); t7=csub(v[3],v[7]);
  }
  t5 = make_float2(C7*(t5.x - sg*t5.y), C7*(t5.y + sg*t5.x));
  t6 = make_float2(-sg*t6.y, sg*t6.x);
  t7 = make_float2(C7*(-t7.x - sg*t7.y), C7*(sg*t7.x - t7.y));
  float2 u0=cadd(t0,t2), u2=csub(t0,t2);
  float2 u1=cadd(t1,t3), u3=csub(t1,t3);
  u3 = make_float2(-sg*u3.y, sg*u3.x);
  float2 u4=cadd(t4,t6), u6=csub(t4,t6);
  float2 u5=cadd(t5,t7), u7=csub(t5,t7);
  u7 = make_float2(-sg*u7.y, sg*u7.x);
  v[0]=cadd(u0,u1); v[4]=csub(u0,u1);
  v[2]=cadd(u2,u3); v[6]=csub(u2,u3);
  v[1]=cadd(u4,u5); v[5]=csub(u4,u5);
  v[3]=cadd(u6,u7); v[7]=csub(u6,u7);
}

// One-wave FFT-512; xch = per-wave float2[544] (16B aligned). Wave-sync only.
template<int S, bool ZTOP>
__device__ inline void wfft512(float2 v[8], int lane, float2* xch,
                               const float2* twt) {
  const int p2 = lane & 7, u0 = lane >> 3;
  dft8<S, ZTOP>(v);
  { float2 t1 = twsgn(twt[lane], S), acc = t1;
    v[1] = cmul(v[1], acc);
    #pragma unroll
    for (int u = 2; u < 8; u++) { acc = cmul(acc, t1); v[u] = cmul(v[u], acc); } }
  __builtin_amdgcn_wave_barrier();
  #pragma unroll
  for (int u = 0; u < 8; u++) xch[u*68 + p2*8 + u0] = v[u];
  __builtin_amdgcn_wave_barrier();
  { const float4* rp = (const float4*)(xch + u0*68 + p2*8);
    #pragma unroll
    for (int q = 0; q < 4; q++) {
      float4 t = rp[q];
      v[2*q]   = make_float2(t.x, t.y);
      v[2*q+1] = make_float2(t.z, t.w);
    } }
  dft8<S, false>(v);
  { float2 t1 = twsgn(twt[p2 << 3], S), acc = t1;
    v[1] = cmul(v[1], acc);
    #pragma unroll
    for (int u = 2; u < 8; u++) { acc = cmul(acc, t1); v[u] = cmul(v[u], acc); } }
  __builtin_amdgcn_wave_barrier();
  #pragma unroll
  for (int u = 0; u < 8; u++) xch[u*68 + lane] = v[u];
  __builtin_amdgcn_wave_barrier();
  { const float4* rp = (const float4*)(xch + p2*68 + u0*8);
    #pragma unroll
    for (int q = 0; q < 4; q++) {
      float4 t = rp[q];
      v[2*q]   = make_float2(t.x, t.y);
      v[2*q+1] = make_float2(t.z, t.w);
    } }
  dft8<S, false>(v);
}

__global__ void __launch_bounds__(256, 4)
k_fused(const float* __restrict__ mask, const float* __restrict__ prm,
        const float* __restrict__ sfx, const float* __restrict__ sfy,
        char* ws, float2* R1t, float2* Wg, __half2* T2, float* acc,
        float* out, int CH) {
  const int t = threadIdx.x, lane = t & 63, wv = t >> 6;
  const unsigned nblk = gridDim.x;
  char* bar = ws + O_BAR;
  unsigned ep = 0;
  __shared__ __align__(16) float2 lds[4*544];
  __shared__ __align__(16) float2 twt[512];
  __shared__ float FMt[241];
  build_twt(twt);
  if (t < 241) FMt[t] = (float)(((double)(t - 120)) / 100.0);
  float2* const xch = lds + wv*544;

  // ---------------- phase B1: setup (block 0) + row FFTs -------------------
  if (blockIdx.x == 0) {
    float*  sw  = (float*)lds;                 // scratch overlay (pre-FFT)
    float*  sxx = sw + 192; float* syy = sxx + 192; float* scw = syy + 192;
    double* so  = (double*)(sw + 768);
    int*    skp = (int*)(so + 176);
    if (t < 169) {
      float p = prm[t];
      float val = 1.f / (1.f + __expf(-8.f * p));
      float w = (val >= 0.001f) ? val : 0.f;
      double o = 0.0; float fx = 0.f, fy = 0.f;
      if (w > 0.f) {
        fx = sfx[t]; fy = sfy[t];
        double f2 = (double)fx*(double)fx + (double)fy*(double)fy;
        o = (double)w * sqrt((1.0 - 0.11390625 * f2) / (1.0 - 0.87890625 * f2));
      }
      sw[t] = w; so[t] = o; sxx[t] = fx; syy[t] = fy;
    }
    __syncthreads();
    if (t < 169) {                      // merge s with s'=(-fx,-fy): exact
      float w = sw[t];
      int keep = 0; float cw = w;
      if (w > 0.f) {
        float fx = sxx[t], fy = syy[t];
        int pr = -1;
        for (int s2 = 0; s2 < 169; s2++) {
          if (sw[s2] > 0.f && fabsf(sxx[s2] + fx) < 1e-5f
                           && fabsf(syy[s2] + fy) < 1e-5f) { pr = s2; break; }
        }
        if (pr < 0 || pr == t) keep = 1;
        else if (pr > t) { keep = 1; cw = w + sw[pr]; }
      }
      skp[t] = keep; scw[t] = cw;
    }
    __syncthreads();
    if (t == 0) {
      float* wsfw = (float*)ws;
      double Sden = 0.0; int c = 0;
      for (int s = 0; s < 169; s++) {
        Sden += so[s];                               // norm over ALL valid
        if (skp[s]) {
          st_sys_f(wsfw + 64 + c,  scw[s]);
          st_sys_f(wsfw + 320 + c, sxx[s]);
          st_sys_f(wsfw + 576 + c, syy[s]);
          c++;
        }
      }
      st_sys_i((int*)ws, c);
      st_sys_f(wsfw + 1, (float)(1.0 / (262144.0 * 1.44 * Sden)));  // 512^2 refold
    }
  }
  __syncthreads();                              // setup scratch dead; twt ready
  for (int rb = blockIdx.x; rb < 128; rb += nblk) {
    int y = rb * 4 + wv;
    float2 v[8];
    #pragma unroll
    for (int q = 0; q < 8; q++) v[q] = make_float2(mask[y*512 + 64*q + lane], 0.f);
    wfft512<-1, false>(v, lane, xch, twt);
    #pragma unroll
    for (int u = 0; u < 8; u++) {
      int k = (lane>>3) + 8*(lane&7) + 64*u;
      int beta = (k >= 392) ? (k - 392) : ((k <= 120) ? (k + 120) : -1);
      if (beta >= 0) st_sys_f2(R1t + beta*512 + y, v[u]);
    }
  }
  gbar(bar, nblk, ep);

  // ---------------- phase B2: col FFT -> W[alpha][beta] --------------------
  for (int jb = blockIdx.x; jb < 61; jb += nblk) {
    int j = jb * 4 + wv;                        // beta 0..243
    float2 v[8];
    #pragma unroll
    for (int q = 0; q < 8; q++)
      v[q] = (j < 241) ? ld_sys_f2(R1t + j*512 + 64*q + lane)
                       : make_float2(0.f, 0.f);
    wfft512<-1, false>(v, lane, xch, twt);
    if (j < 241) {
      #pragma unroll
      for (int u = 0; u < 8; u++) {
        int k = (lane>>3) + 8*(lane&7) + 64*u;
        int alpha = (k >= 392) ? (k - 392) : ((k <= 120) ? (k + 120) : -1);
        if (alpha >= 0) st_sys_f2(Wg + alpha*241 + j, v[u]);
      }
    }
  }
  gbar(bar, nblk, ep);

  const float* wsf = (const float*)ws;
  const int count = ld_sys_i((const int*)ws);
  int nb = (count + CH - 1) / CH;
  if (nb < 1) nb = 1;                           // count==0 still zero-fills acc
  for (int bi = 0; bi < nb; bi++) {
    const int base = bi * CH;
    int active = count - base;
    if (active > CH) active = CH;
    if (active < 0) active = 0;
    const int ntask = active * 31;

    // -------- phase C1: row IDFT of (W.*P)*sqrt(w)/512 -> T2 fp16 ---------
    for (int task = blockIdx.x; task < ntask; task += nblk) {
      int sic  = task / 31;
      int tile = task % 31;                    // 8 alphas/tile, 2 phases of 4
      int slot = base + sic;
      float fx = ld_sys_f(wsf + 320 + slot), fy = ld_sys_f(wsf + 576 + slot);
      float sqw = __fsqrt_rn(ld_sys_f(wsf + 64 + slot)) * 0.001953125f;
      #pragma unroll
      for (int ph = 0; ph < 2; ph++) {
        int alpha = tile*8 + ph*4 + wv;
        bool arow = (alpha < 241);
        float Gf = __fadd_rn(arow ? FMt[alpha] : 0.f, fy);
        float g2 = __fmul_rn(Gf, Gf);
        bool active_row = arow && (g2 <= 1.0f); // fl(G^2)>1 -> row all-zero
        float2 v[8];
        #pragma unroll
        for (int q = 0; q < 8; q++) v[q] = make_float2(0.f, 0.f);
        if (active_row) {
          #pragma unroll
          for (int q = 0; q < 4; q++) {        // n<241 -> q<4 only
            int n = 64*q + lane;
            if (n < 241) {
              float Ff = __fadd_rn(FMt[n], fx);
              float r2 = __fadd_rn(__fmul_rn(Ff, Ff), g2);  // np f32 semantics
              if (r2 <= 1.0f) {
                float num = fmaf(-0.11390625f, r2, 1.0f);
                float den = fmaf(-0.87890625f, r2, 1.0f);
                float P = __fsqrt_rn(__fsqrt_rn(__fdividef(num, den))) * sqw;
                float2 Wv = ld_sys_f2(Wg + alpha*241 + n);
                v[q] = make_float2(P * Wv.x, P * Wv.y);
              }
            }
          }
          wfft512<1, true>(v, lane, xch, twt);
        }
        #pragma unroll
        for (int u = 0; u < 8; u++) {
          int xx = (lane>>3) + 8*(lane&7) + 64*u;
          xch[xx] = v[u];                      // zeros when inactive
        }
        __syncthreads();
        int colb = tile*8 + ph*4;
        if (colb < 244) {                      // tile30/ph1 would spill: skip
          #pragma unroll
          for (int r = 0; r < 2; r++) {
            int x = t + 256*r;
            union { __half2 h[4]; float4 f; } uu;
            #pragma unroll
            for (int wvi = 0; wvi < 4; wvi++) {
              float2 a = lds[wvi*544 + x];
              uu.h[wvi] = __floats2half2_rn(a.x, a.y);
            }
            // T2 layout [sic][x][col] (C2-read-coalesced)
            st_sys_f4(T2 + ((size_t)sic*512 + x)*244 + colb, uu.f);
          }
        }
        __syncthreads();
      }
    }
    gbar(bar, nblk, ep);

    // -------- phase C2: col IDFT per source, acc += |AA'|^2 ---------------
    for (int unit = blockIdx.x; unit < 1024; unit += nblk) {
      int part = unit & 7;
      int x = (unit >> 3) * 4 + wv;
      float av[8] = {0.f,0.f,0.f,0.f,0.f,0.f,0.f,0.f};
      int sic = part;
      bool act = (sic < CH) && (base + sic < count);
      __half2 pv[4] = {{0.f,0.f},{0.f,0.f},{0.f,0.f},{0.f,0.f}};
      if (act) {
        const __half2* row = T2 + ((size_t)sic*512 + x)*244;
        #pragma unroll
        for (int q = 0; q < 4; q++) {
          int n = 64*q + lane;
          pv[q] = (n < 241) ? ld_sys_h2(row + n) : __half2{0.f, 0.f};
        }
      }
      while (act) {
        float2 v[8];
        #pragma unroll
        for (int q = 0; q < 4; q++) v[q] = __half22float2(pv[q]);
        #pragma unroll
        for (int q = 4; q < 8; q++) v[q] = make_float2(0.f, 0.f);
        int nsic = sic + SPLIT;
        act = (nsic < CH) && (base + nsic < count);
        if (act) {                             // prefetch across the FFT
          const __half2* row = T2 + ((size_t)nsic*512 + x)*244;
          #pragma unroll
          for (int q = 0; q < 4; q++) {
            int n = 64*q + lane;
            pv[q] = (n < 241) ? ld_sys_h2(row + n) : __half2{0.f, 0.f};
          }
        }
        wfft512<1, true>(v, lane, xch, twt);
        #pragma unroll
        for (int u = 0; u < 8; u++)
          av[u] += fmaf(v[u].x, v[u].x, v[u].y*v[u].y);
        sic = nsic;
      }
      float* a = acc + ((size_t)part << 18) + (size_t)x * 512;
      int y0 = (lane>>3) + 8*(lane&7);
      if (bi == 0) {
        #pragma unroll
        for (int u = 0; u < 8; u++) st_sys_f(a + y0 + 64*u, av[u]);
      } else {
        #pragma unroll
        for (int u = 0; u < 8; u++) {
          float prev = ld_sys_f(a + y0 + 64*u);
          st_sys_f(a + y0 + 64*u, prev + av[u]);
        }
      }
    }
    gbar(bar, nblk, ep);
  }

  // ---------------- phase D: transpose, scale, doses, resist ---------------
  {
    float scale = ld_sys_f(wsf + 1);
    float (*tile2)[33] = reinterpret_cast<float(*)[33]>((float*)lds);
    const float dd[3] = {0.9604f, 1.0f, 1.0404f};
    int tx = t & 31, ty0 = t >> 5;
    for (int tb = blockIdx.x; tb < 256; tb += nblk) {
      int x0 = (tb & 15) * 32, y0 = (tb >> 4) * 32;
      #pragma unroll
      for (int r = 0; r < 4; r++) {
        int i = ty0 + 8*r;
        const float* ap = acc + (size_t)(x0 + i)*512 + y0 + tx;
        float s = 0.f;
        #pragma unroll
        for (int p = 0; p < SPLIT; p++) s += ld_sys_f(ap + ((size_t)p << 18));
        tile2[i][tx] = s;
      }
      __syncthreads();
      #pragma unroll
      for (int r = 0; r < 4; r++) {
        int yy = ty0 + 8*r;
        float I = scale * tile2[tx][yy];
        int o = (y0 + yy)*512 + x0 + tx;
        #pragma unroll
        for (int d = 0; d < 3; d++) {
          float Ik = dd[d] * I;
          out[(size_t)d*262144 + o] = Ik;
          out[(size_t)(3+d)*262144 + o] = 1.f / (1.f + __expf(-30.f*(Ik - 0.225f)));
        }
      }
      __syncthreads();
    }
  }
}

extern "C" void kernel_launch(void* const* d_in, const int* in_sizes, int n_in,
                              void* d_out, int out_size, void* d_ws, size_t ws_size,
                              hipStream_t stream) {
  (void)in_sizes; (void)n_in; (void)out_size;
  const float* mask = (const float*)d_in[0];
  const float* prm  = (const float*)d_in[1];
  const float* sfx  = (const float*)d_in[2];
  const float* sfy  = (const float*)d_in[3];
  float* out = (float*)d_out;
  char*  ws  = (char*)d_ws;

  float*   acc = (float*)(ws + O_ACC);
  float2*  Wg  = (float2*)(ws + O_WIN);
  float2*  R1t = (float2*)(ws + O_R1);
  __half2* T2  = (__half2*)(ws + O_T2);

  size_t avail = (ws_size > O_T2) ? (ws_size - O_T2) : 0;
  int CH = (int)(avail / SLOT_BYTES);
  if (CH > 169) CH = 169;
  if (CH < 1)   CH = 1;

  // Cooperative grid: occupancy-derived, multiple of 32 (tree groups),
  // capped at 1024.
  static int grid_blocks = 0;
  if (grid_blocks == 0) {
    int nbk = 0;
    if (hipOccupancyMaxActiveBlocksPerMultiprocessor(
            &nbk, (const void*)k_fused, 256, 0) != hipSuccess || nbk < 1)
      nbk = 1;
    int ncu = 256;
    hipDeviceProp_t prop;
    int dev = 0;
    if (hipGetDevice(&dev) == hipSuccess &&
        hipGetDeviceProperties(&prop, dev) == hipSuccess &&
        prop.multiProcessorCount > 0)
      ncu = prop.multiProcessorCount;
    long g = (long)nbk * (long)ncu;
    if (g > 1024) g = 1024;
    g &= ~31L;                                  // multiple of 32 for the tree
    if (g < 32) g = 32;
    grid_blocks = (int)g;
  }

  // Zero the barrier region (captured; ws is re-poisoned every iteration).
  hipMemsetAsync(ws + O_BAR, 0, 24576, stream);

  void* args[] = { (void*)&mask, (void*)&prm, (void*)&sfx, (void*)&sfy,
                   (void*)&ws, (void*)&R1t, (void*)&Wg, (void*)&T2,
                   (void*)&acc, (void*)&out, (void*)&CH };
  hipLaunchCooperativeKernel((const void*)k_fused, dim3(grid_blocks), dim3(256),
                             args, 0, stream);
}

// Round 6
// 152.131 us; speedup vs baseline: 2.2979x; 1.1507x over previous
//
#include <hip/hip_runtime.h>
#include <hip/hip_fp16.h>

// ---------------------------------------------------------------------------
// Abbe lithography forward — single PLAIN-launched persistent kernel,
// fence-free tree grid-barrier + system-scope (sc0 sc1) cross-phase data.
// History: cg::grid.sync ~95us/sync (R1); flat atomic+threadfence ~95us
// (R2); tree+threadfence ~60us (R3); fence-free tree + uncached cross-phase
// data -> kernel 107us, bench 175us (R4; ~65us = cooperative-launch
// overhead). R5 (plain launch, grid = exact residency capacity 1024)
// hung the container: spin barrier at exact capacity deadlocks if ANY
// block fails to become resident. R6: plain launch with a hard margin —
// grid = (occupancy-1) blocks/CU = 768 < 1024 capacity, so all blocks are
// co-resident with 1 block/CU headroom; spin barrier safe by construction.
// Math identical to the verified 5-kernel version (absmax 0.00390625).
// Phases: B1 row FFT (+block0 setup) -> bar -> B2 col FFT -> bar ->
//         C1 row IDFT -> bar -> C2 col IDFT+|.|^2 -> bar -> D finalize.
// FFT-512: radix-8, 3 stages, one wave per FFT, wave-level sync only.
// ---------------------------------------------------------------------------

#define SPLIT 8

static const size_t O_BAR  = 4096;                 // 24KB barrier region
//   gcnt[g] @ O_BAR + g*256        (g < 32)
//   ggen[g] @ O_BAR + 8192 + g*256
//   rcnt    @ O_BAR + 16384
//   rgen    @ O_BAR + 16640
static const size_t O_ACC  = 32768;                // SPLIT*512*512*f32
static const size_t ACC_BYTES = (size_t)SPLIT * 512 * 512 * 4;
static const size_t O_WIN  = O_ACC + ACC_BYTES;
static const size_t O_R1   = O_WIN + 464896;
static const size_t O_T2   = O_R1 + 987136;
static const size_t SLOT_BYTES = (size_t)512 * 244 * 4;  // half2 slots

// ---- system-scope (coherence-point) load/store helpers --------------------
__device__ inline void st_sys_f(float* p, float v) {
  __hip_atomic_store((unsigned*)p, __float_as_uint(v),
                     __ATOMIC_RELAXED, __HIP_MEMORY_SCOPE_SYSTEM);
}
__device__ inline float ld_sys_f(const float* p) {
  return __uint_as_float(__hip_atomic_load((const unsigned*)p,
                     __ATOMIC_RELAXED, __HIP_MEMORY_SCOPE_SYSTEM));
}
__device__ inline void st_sys_i(int* p, int v) {
  __hip_atomic_store(p, v, __ATOMIC_RELAXED, __HIP_MEMORY_SCOPE_SYSTEM);
}
__device__ inline int ld_sys_i(const int* p) {
  return __hip_atomic_load(p, __ATOMIC_RELAXED, __HIP_MEMORY_SCOPE_SYSTEM);
}
__device__ inline void st_sys_f2(float2* p, float2 v) {
  union { float2 f; unsigned long long u; } c; c.f = v;
  __hip_atomic_store((unsigned long long*)p, c.u,
                     __ATOMIC_RELAXED, __HIP_MEMORY_SCOPE_SYSTEM);
}
__device__ inline float2 ld_sys_f2(const float2* p) {
  union { unsigned long long u; float2 f; } c;
  c.u = __hip_atomic_load((const unsigned long long*)p,
                     __ATOMIC_RELAXED, __HIP_MEMORY_SCOPE_SYSTEM);
  return c.f;
}
__device__ inline void st_sys_f4(void* p, float4 v) {
  union { float2 f; unsigned long long u; } a, b;
  a.f = make_float2(v.x, v.y); b.f = make_float2(v.z, v.w);
  unsigned long long* q = (unsigned long long*)p;
  __hip_atomic_store(q,     a.u, __ATOMIC_RELAXED, __HIP_MEMORY_SCOPE_SYSTEM);
  __hip_atomic_store(q + 1, b.u, __ATOMIC_RELAXED, __HIP_MEMORY_SCOPE_SYSTEM);
}
__device__ inline __half2 ld_sys_h2(const __half2* p) {
  union { unsigned u; __half2 h; } c;
  c.u = __hip_atomic_load((const unsigned*)p,
                     __ATOMIC_RELAXED, __HIP_MEMORY_SCOPE_SYSTEM);
  return c.h;
}

__device__ inline float2 cadd(float2 a, float2 b){ return make_float2(a.x+b.x, a.y+b.y); }
__device__ inline float2 csub(float2 a, float2 b){ return make_float2(a.x-b.x, a.y-b.y); }
__device__ inline float2 cmul(float2 a, float2 b){
  return make_float2(fmaf(a.x, b.x, -(a.y*b.y)), fmaf(a.x, b.y, a.y*b.x));
}
__device__ inline float2 twsgn(float2 t, int S) {
  return make_float2(t.x, (S > 0) ? t.y : -t.y);
}

// Fence-free two-level tree grid-barrier (nblk multiple of 32).
// All counters/gens at system scope (coherence point). No wbl2/inv: cross-
// phase data is itself system-scope, vmcnt(0) = stores at coherence point.
__device__ inline void gbar(char* bar, unsigned nblk, unsigned& ep) {
  __syncthreads();                 // compiler emits vmcnt(0) before s_barrier
  ep++;
  if (threadIdx.x == 0) {
    const unsigned target = ep;
    const unsigned g    = blockIdx.x >> 5;
    const unsigned ngrp = nblk >> 5;
    unsigned* gcnt = (unsigned*)(bar + (size_t)g * 256);
    unsigned* ggen = (unsigned*)(bar + 8192 + (size_t)g * 256);
    unsigned* rcnt = (unsigned*)(bar + 16384);
    unsigned* rgen = (unsigned*)(bar + 16640);
    asm volatile("s_waitcnt vmcnt(0)" ::: "memory");
    unsigned old = __hip_atomic_fetch_add(gcnt, 1u, __ATOMIC_RELAXED,
                                          __HIP_MEMORY_SCOPE_SYSTEM);
    if (old == 31u) {                          // group leader
      __hip_atomic_store(gcnt, 0u, __ATOMIC_RELAXED, __HIP_MEMORY_SCOPE_SYSTEM);
      unsigned r = __hip_atomic_fetch_add(rcnt, 1u, __ATOMIC_RELAXED,
                                          __HIP_MEMORY_SCOPE_SYSTEM);
      if (r == ngrp - 1u) {                    // last group: release root
        __hip_atomic_store(rcnt, 0u, __ATOMIC_RELAXED, __HIP_MEMORY_SCOPE_SYSTEM);
        __hip_atomic_store(rgen, target, __ATOMIC_RELAXED,
                           __HIP_MEMORY_SCOPE_SYSTEM);
      } else {
        while (__hip_atomic_load(rgen, __ATOMIC_RELAXED,
                                 __HIP_MEMORY_SCOPE_SYSTEM) < target)
          __builtin_amdgcn_s_sleep(1);
      }
      __hip_atomic_store(ggen, target, __ATOMIC_RELAXED,
                         __HIP_MEMORY_SCOPE_SYSTEM);
    } else {
      while (__hip_atomic_load(ggen, __ATOMIC_RELAXED,
                               __HIP_MEMORY_SCOPE_SYSTEM) < target)
        __builtin_amdgcn_s_sleep(2);
    }
  }
  __syncthreads();
}

// Per-block twiddle table exp(+2*pi*i*k/512), f64-built (256-thread blocks).
__device__ inline void build_twt(float2* twt) {
  for (int k = (int)threadIdx.x; k < 512; k += 256) {
    double a = 6.283185307179586476925286766559 * (double)k / 512.0;
    twt[k] = make_float2((float)cos(a), (float)sin(a));
  }
}

// Radix-8 butterfly. If ZTOP, v[4..7] are known zero (skips first add level).
template<int S, bool ZTOP>
__device__ inline void dft8(float2 v[8]) {
  const float sg = (float)S;
  const float C7 = 0.7071067811865476f;
  float2 t0, t1, t2, t3, t4, t5, t6, t7;
  if (ZTOP) {
    t0 = v[0]; t4 = v[0];
    t1 = v[1]; t5 = v[1];
    t2 = v[2]; t6 = v[2];
    t3 = v[3]; t7 = v[3];
  } else {
    t0=cadd(v[0],v[4]); t4=csub(v[0],v[4]);
    t1=cadd(v[1],v[5]); t5=csub(v[1],v[5]);
    t2=cadd(v[2],v[6]); t6=csub(v[2],v[6]);
    t3=cadd(v[3],v[7]); t7=csub(v[3],v[7]);
  }
  t5 = make_float2(C7*(t5.x - sg*t5.y), C7*(t5.y + sg*t5.x));
  t6 = make_float2(-sg*t6.y, sg*t6.x);
  t7 = make_float2(C7*(-t7.x - sg*t7.y), C7*(sg*t7.x - t7.y));
  float2 u0=cadd(t0,t2), u2=csub(t0,t2);
  float2 u1=cadd(t1,t3), u3=csub(t1,t3);
  u3 = make_float2(-sg*u3.y, sg*u3.x);
  float2 u4=cadd(t4,t6), u6=csub(t4,t6);
  float2 u5=cadd(t5,t7), u7=csub(t5,t7);
  u7 = make_float2(-sg*u7.y, sg*u7.x);
  v[0]=cadd(u0,u1); v[4]=csub(u0,u1);
  v[2]=cadd(u2,u3); v[6]=csub(u2,u3);
  v[1]=cadd(u4,u5); v[5]=csub(u4,u5);
  v[3]=cadd(u6,u7); v[7]=csub(u6,u7);
}

// One-wave FFT-512; xch = per-wave float2[544] (16B aligned). Wave-sync only.
template<int S, bool ZTOP>
__device__ inline void wfft512(float2 v[8], int lane, float2* xch,
                               const float2* twt) {
  const int p2 = lane & 7, u0 = lane >> 3;
  dft8<S, ZTOP>(v);
  { float2 t1 = twsgn(twt[lane], S), acc = t1;
    v[1] = cmul(v[1], acc);
    #pragma unroll
    for (int u = 2; u < 8; u++) { acc = cmul(acc, t1); v[u] = cmul(v[u], acc); } }
  __builtin_amdgcn_wave_barrier();
  #pragma unroll
  for (int u = 0; u < 8; u++) xch[u*68 + p2*8 + u0] = v[u];
  __builtin_amdgcn_wave_barrier();
  { const float4* rp = (const float4*)(xch + u0*68 + p2*8);
    #pragma unroll
    for (int q = 0; q < 4; q++) {
      float4 t = rp[q];
      v[2*q]   = make_float2(t.x, t.y);
      v[2*q+1] = make_float2(t.z, t.w);
    } }
  dft8<S, false>(v);
  { float2 t1 = twsgn(twt[p2 << 3], S), acc = t1;
    v[1] = cmul(v[1], acc);
    #pragma unroll
    for (int u = 2; u < 8; u++) { acc = cmul(acc, t1); v[u] = cmul(v[u], acc); } }
  __builtin_amdgcn_wave_barrier();
  #pragma unroll
  for (int u = 0; u < 8; u++) xch[u*68 + lane] = v[u];
  __builtin_amdgcn_wave_barrier();
  { const float4* rp = (const float4*)(xch + p2*68 + u0*8);
    #pragma unroll
    for (int q = 0; q < 4; q++) {
      float4 t = rp[q];
      v[2*q]   = make_float2(t.x, t.y);
      v[2*q+1] = make_float2(t.z, t.w);
    } }
  dft8<S, false>(v);
}

__global__ void __launch_bounds__(256, 4)
k_fused(const float* __restrict__ mask, const float* __restrict__ prm,
        const float* __restrict__ sfx, const float* __restrict__ sfy,
        char* ws, float2* R1t, float2* Wg, __half2* T2, float* acc,
        float* out, int CH) {
  const int t = threadIdx.x, lane = t & 63, wv = t >> 6;
  const unsigned nblk = gridDim.x;
  char* bar = ws + O_BAR;
  unsigned ep = 0;
  __shared__ __align__(16) float2 lds[4*544];
  __shared__ __align__(16) float2 twt[512];
  __shared__ float FMt[241];
  build_twt(twt);
  if (t < 241) FMt[t] = (float)(((double)(t - 120)) / 100.0);
  float2* const xch = lds + wv*544;

  // ---------------- phase B1: setup (block 0) + row FFTs -------------------
  if (blockIdx.x == 0) {
    float*  sw  = (float*)lds;                 // scratch overlay (pre-FFT)
    float*  sxx = sw + 192; float* syy = sxx + 192; float* scw = syy + 192;
    double* so  = (double*)(sw + 768);
    int*    skp = (int*)(so + 176);
    if (t < 169) {
      float p = prm[t];
      float val = 1.f / (1.f + __expf(-8.f * p));
      float w = (val >= 0.001f) ? val : 0.f;
      double o = 0.0; float fx = 0.f, fy = 0.f;
      if (w > 0.f) {
        fx = sfx[t]; fy = sfy[t];
        double f2 = (double)fx*(double)fx + (double)fy*(double)fy;
        o = (double)w * sqrt((1.0 - 0.11390625 * f2) / (1.0 - 0.87890625 * f2));
      }
      sw[t] = w; so[t] = o; sxx[t] = fx; syy[t] = fy;
    }
    __syncthreads();
    if (t < 169) {                      // merge s with s'=(-fx,-fy): exact
      float w = sw[t];
      int keep = 0; float cw = w;
      if (w > 0.f) {
        float fx = sxx[t], fy = syy[t];
        int pr = -1;
        for (int s2 = 0; s2 < 169; s2++) {
          if (sw[s2] > 0.f && fabsf(sxx[s2] + fx) < 1e-5f
                           && fabsf(syy[s2] + fy) < 1e-5f) { pr = s2; break; }
        }
        if (pr < 0 || pr == t) keep = 1;
        else if (pr > t) { keep = 1; cw = w + sw[pr]; }
      }
      skp[t] = keep; scw[t] = cw;
    }
    __syncthreads();
    if (t == 0) {
      float* wsfw = (float*)ws;
      double Sden = 0.0; int c = 0;
      for (int s = 0; s < 169; s++) {
        Sden += so[s];                               // norm over ALL valid
        if (skp[s]) {
          st_sys_f(wsfw + 64 + c,  scw[s]);
          st_sys_f(wsfw + 320 + c, sxx[s]);
          st_sys_f(wsfw + 576 + c, syy[s]);
          c++;
        }
      }
      st_sys_i((int*)ws, c);
      st_sys_f(wsfw + 1, (float)(1.0 / (262144.0 * 1.44 * Sden)));  // 512^2 refold
    }
    __syncthreads();                            // setup scratch dead before FFT use
  }
  // Row FFTs: when grid is large enough, block 0 does none (its serial
  // setup overlaps the other blocks' FFTs instead of trailing them).
  {
    int rb0, step;
    if (nblk > 128) { rb0 = (int)blockIdx.x - 1; step = (int)nblk - 1; }
    else            { rb0 = (int)blockIdx.x;     step = (int)nblk; }
    if (rb0 >= 0) {
      for (int rb = rb0; rb < 128; rb += step) {
        int y = rb * 4 + wv;
        float2 v[8];
        #pragma unroll
        for (int q = 0; q < 8; q++) v[q] = make_float2(mask[y*512 + 64*q + lane], 0.f);
        wfft512<-1, false>(v, lane, xch, twt);
        #pragma unroll
        for (int u = 0; u < 8; u++) {
          int k = (lane>>3) + 8*(lane&7) + 64*u;
          int beta = (k >= 392) ? (k - 392) : ((k <= 120) ? (k + 120) : -1);
          if (beta >= 0) st_sys_f2(R1t + beta*512 + y, v[u]);
        }
      }
    }
  }
  gbar(bar, nblk, ep);

  // ---------------- phase B2: col FFT -> W[alpha][beta] --------------------
  for (int jb = blockIdx.x; jb < 61; jb += nblk) {
    int j = jb * 4 + wv;                        // beta 0..243
    float2 v[8];
    #pragma unroll
    for (int q = 0; q < 8; q++)
      v[q] = (j < 241) ? ld_sys_f2(R1t + j*512 + 64*q + lane)
                       : make_float2(0.f, 0.f);
    wfft512<-1, false>(v, lane, xch, twt);
    if (j < 241) {
      #pragma unroll
      for (int u = 0; u < 8; u++) {
        int k = (lane>>3) + 8*(lane&7) + 64*u;
        int alpha = (k >= 392) ? (k - 392) : ((k <= 120) ? (k + 120) : -1);
        if (alpha >= 0) st_sys_f2(Wg + alpha*241 + j, v[u]);
      }
    }
  }
  gbar(bar, nblk, ep);

  const float* wsf = (const float*)ws;
  const int count = ld_sys_i((const int*)ws);
  int nb = (count + CH - 1) / CH;
  if (nb < 1) nb = 1;                           // count==0 still zero-fills acc
  for (int bi = 0; bi < nb; bi++) {
    const int base = bi * CH;
    int active = count - base;
    if (active > CH) active = CH;
    if (active < 0) active = 0;
    const int ntask = active * 31;

    // -------- phase C1: row IDFT of (W.*P)*sqrt(w)/512 -> T2 fp16 ---------
    for (int task = blockIdx.x; task < ntask; task += nblk) {
      int sic  = task / 31;
      int tile = task % 31;                    // 8 alphas/tile, 2 phases of 4
      int slot = base + sic;
      float fx = ld_sys_f(wsf + 320 + slot), fy = ld_sys_f(wsf + 576 + slot);
      float sqw = __fsqrt_rn(ld_sys_f(wsf + 64 + slot)) * 0.001953125f;
      #pragma unroll
      for (int ph = 0; ph < 2; ph++) {
        int alpha = tile*8 + ph*4 + wv;
        bool arow = (alpha < 241);
        float Gf = __fadd_rn(arow ? FMt[alpha] : 0.f, fy);
        float g2 = __fmul_rn(Gf, Gf);
        bool active_row = arow && (g2 <= 1.0f); // fl(G^2)>1 -> row all-zero
        float2 v[8];
        #pragma unroll
        for (int q = 0; q < 8; q++) v[q] = make_float2(0.f, 0.f);
        if (active_row) {
          #pragma unroll
          for (int q = 0; q < 4; q++) {        // n<241 -> q<4 only
            int n = 64*q + lane;
            if (n < 241) {
              float Ff = __fadd_rn(FMt[n], fx);
              float r2 = __fadd_rn(__fmul_rn(Ff, Ff), g2);  // np f32 semantics
              if (r2 <= 1.0f) {
                float num = fmaf(-0.11390625f, r2, 1.0f);
                float den = fmaf(-0.87890625f, r2, 1.0f);
                float P = __fsqrt_rn(__fsqrt_rn(__fdividef(num, den))) * sqw;
                float2 Wv = ld_sys_f2(Wg + alpha*241 + n);
                v[q] = make_float2(P * Wv.x, P * Wv.y);
              }
            }
          }
          wfft512<1, true>(v, lane, xch, twt);
        }
        #pragma unroll
        for (int u = 0; u < 8; u++) {
          int xx = (lane>>3) + 8*(lane&7) + 64*u;
          xch[xx] = v[u];                      // zeros when inactive
        }
        __syncthreads();
        int colb = tile*8 + ph*4;
        if (colb < 244) {                      // tile30/ph1 would spill: skip
          #pragma unroll
          for (int r = 0; r < 2; r++) {
            int x = t + 256*r;
            union { __half2 h[4]; float4 f; } uu;
            #pragma unroll
            for (int wvi = 0; wvi < 4; wvi++) {
              float2 a = lds[wvi*544 + x];
              uu.h[wvi] = __floats2half2_rn(a.x, a.y);
            }
            // T2 layout [sic][x][col] (C2-read-coalesced)
            st_sys_f4(T2 + ((size_t)sic*512 + x)*244 + colb, uu.f);
          }
        }
        __syncthreads();
      }
    }
    gbar(bar, nblk, ep);

    // -------- phase C2: col IDFT per source, acc += |AA'|^2 ---------------
    for (int unit = blockIdx.x; unit < 1024; unit += nblk) {
      int part = unit & 7;
      int x = (unit >> 3) * 4 + wv;
      float av[8] = {0.f,0.f,0.f,0.f,0.f,0.f,0.f,0.f};
      int sic = part;
      bool act = (sic < CH) && (base + sic < count);
      __half2 pv[4] = {{0.f,0.f},{0.f,0.f},{0.f,0.f},{0.f,0.f}};
      if (act) {
        const __half2* row = T2 + ((size_t)sic*512 + x)*244;
        #pragma unroll
        for (int q = 0; q < 4; q++) {
          int n = 64*q + lane;
          pv[q] = (n < 241) ? ld_sys_h2(row + n) : __half2{0.f, 0.f};
        }
      }
      while (act) {
        float2 v[8];
        #pragma unroll
        for (int q = 0; q < 4; q++) v[q] = __half22float2(pv[q]);
        #pragma unroll
        for (int q = 4; q < 8; q++) v[q] = make_float2(0.f, 0.f);
        int nsic = sic + SPLIT;
        act = (nsic < CH) && (base + nsic < count);
        if (act) {                             // prefetch across the FFT
          const __half2* row = T2 + ((size_t)nsic*512 + x)*244;
          #pragma unroll
          for (int q = 0; q < 4; q++) {
            int n = 64*q + lane;
            pv[q] = (n < 241) ? ld_sys_h2(row + n) : __half2{0.f, 0.f};
          }
        }
        wfft512<1, true>(v, lane, xch, twt);
        #pragma unroll
        for (int u = 0; u < 8; u++)
          av[u] += fmaf(v[u].x, v[u].x, v[u].y*v[u].y);
        sic = nsic;
      }
      float* a = acc + ((size_t)part << 18) + (size_t)x * 512;
      int y0 = (lane>>3) + 8*(lane&7);
      if (bi == 0) {
        #pragma unroll
        for (int u = 0; u < 8; u++) st_sys_f(a + y0 + 64*u, av[u]);
      } else {
        #pragma unroll
        for (int u = 0; u < 8; u++) {
          float prev = ld_sys_f(a + y0 + 64*u);
          st_sys_f(a + y0 + 64*u, prev + av[u]);
        }
      }
    }
    gbar(bar, nblk, ep);
  }

  // ---------------- phase D: transpose, scale, doses, resist ---------------
  {
    float scale = ld_sys_f(wsf + 1);
    float (*tile2)[33] = reinterpret_cast<float(*)[33]>((float*)lds);
    const float dd[3] = {0.9604f, 1.0f, 1.0404f};
    int tx = t & 31, ty0 = t >> 5;
    for (int tb = blockIdx.x; tb < 256; tb += nblk) {
      int x0 = (tb & 15) * 32, y0 = (tb >> 4) * 32;
      #pragma unroll
      for (int r = 0; r < 4; r++) {
        int i = ty0 + 8*r;
        const float* ap = acc + (size_t)(x0 + i)*512 + y0 + tx;
        float s = 0.f;
        #pragma unroll
        for (int p = 0; p < SPLIT; p++) s += ld_sys_f(ap + ((size_t)p << 18));
        tile2[i][tx] = s;
      }
      __syncthreads();
      #pragma unroll
      for (int r = 0; r < 4; r++) {
        int yy = ty0 + 8*r;
        float I = scale * tile2[tx][yy];
        int o = (y0 + yy)*512 + x0 + tx;
        #pragma unroll
        for (int d = 0; d < 3; d++) {
          float Ik = dd[d] * I;
          out[(size_t)d*262144 + o] = Ik;
          out[(size_t)(3+d)*262144 + o] = 1.f / (1.f + __expf(-30.f*(Ik - 0.225f)));
        }
      }
      __syncthreads();
    }
  }
}

extern "C" void kernel_launch(void* const* d_in, const int* in_sizes, int n_in,
                              void* d_out, int out_size, void* d_ws, size_t ws_size,
                              hipStream_t stream) {
  (void)in_sizes; (void)n_in; (void)out_size;
  const float* mask = (const float*)d_in[0];
  const float* prm  = (const float*)d_in[1];
  const float* sfx  = (const float*)d_in[2];
  const float* sfy  = (const float*)d_in[3];
  float* out = (float*)d_out;
  char*  ws  = (char*)d_ws;

  float*   acc = (float*)(ws + O_ACC);
  float2*  Wg  = (float2*)(ws + O_WIN);
  float2*  R1t = (float2*)(ws + O_R1);
  __half2* T2  = (__half2*)(ws + O_T2);

  size_t avail = (ws_size > O_T2) ? (ws_size - O_T2) : 0;
  int CH = (int)(avail / SLOT_BYTES);
  if (CH > 169) CH = 169;
  if (CH < 1)   CH = 1;

  // Persistent-kernel grid with HARD co-residency margin: (occupancy-1)
  // blocks/CU, so the plain-launch spin barrier can never deadlock on a
  // shaved residency slot (R5 lesson: exact-capacity grid hung the GPU).
  // Multiple of 32 (tree groups), capped at 1024, floor 128 (B1 coverage
  // is grid-strided so any size is correct; >=128 keeps one row per block).
  static int grid_blocks = 0;
  if (grid_blocks == 0) {
    int nbk = 0;
    if (hipOccupancyMaxActiveBlocksPerMultiprocessor(
            &nbk, (const void*)k_fused, 256, 0) != hipSuccess || nbk < 1)
      nbk = 1;
    if (nbk > 1) nbk -= 1;                      // 1 block/CU headroom
    int ncu = 256;
    hipDeviceProp_t prop;
    int dev = 0;
    if (hipGetDevice(&dev) == hipSuccess &&
        hipGetDeviceProperties(&prop, dev) == hipSuccess &&
        prop.multiProcessorCount > 0)
      ncu = prop.multiProcessorCount;
    long g = (long)nbk * (long)ncu;
    if (g > 1024) g = 1024;
    g &= ~31L;                                  // multiple of 32 for the tree
    if (g < 32) g = 32;
    grid_blocks = (int)g;
  }

  // Zero the barrier region (captured; ws is re-poisoned every iteration).
  hipMemsetAsync(ws + O_BAR, 0, 24576, stream);

  k_fused<<<dim3(grid_blocks), dim3(256), 0, stream>>>(
      mask, prm, sfx, sfy, ws, R1t, Wg, T2, acc, out, CH);
}